// Round 2
// baseline (10981.139 us; speedup 1.0000x reference)
//
#include <hip/hip_runtime.h>
#include <math.h>

#define B_ 2048
#define T_ 512
#define D_ 8
#define H_ 64
#define L_ 16
#define P_ 2

// ---- workspace layout (float offsets) ----
#define OFF_AE_IH   0                       // [k=8][j=64][g=4]   = 2048
#define OFF_AE_HH   2048                    // [k=64][j=64][g=4]  = 16384
#define OFF_AD      18432                   // interleaved [k=64][j=64][ih4|hh4] = 32768
#define OFF_WOUT    51200                   // [i=8][d=8][c=8]    = 512
#define OFF_INP0    51712                   // 64
#define OFF_BE      51776                   // 256
#define OFF_BD      52032                   // 256
#define OFF_H0      52288                   // B*H
#define OFF_C0      (OFF_H0 + B_*H_)
#define WS_FLOATS   (OFF_C0 + B_*H_)

__device__ __forceinline__ float sigm(float x) { return 1.0f / (1.0f + __expf(-x)); }
__device__ __forceinline__ float tanhf_(float x) {
  float ax = fabsf(x);
  float e  = __expf(-2.0f * ax);
  float r  = (1.0f - e) / (1.0f + e);
  return copysignf(r, x);
}
__device__ __forceinline__ float lrelu(float x) { return x >= 0.0f ? x : 0.01f * x; }
__device__ __forceinline__ float rdlane(float v, int l) {
  return __int_as_float(__builtin_amdgcn_readlane(__float_as_int(v), l));
}
__device__ __forceinline__ float wsum(float v) {
#pragma unroll
  for (int off = 32; off > 0; off >>= 1) v += __shfl_xor(v, off, 64);
  return v;
}

// ---------------- prep: repack weights / combine biases / start embedding ----------------
struct PrepP {
  const float* W_ih_e; const float* W_hh_e; const float* b_ih_e; const float* b_hh_e;
  const float* W_ih_d; const float* W_hh_d; const float* b_ih_d; const float* b_hh_d;
  const float* W_out;  const float* start;  const float* W_emb;  const float* b_emb;
  float* ws;
};

__global__ __launch_bounds__(256) void prep_kernel(PrepP p) {
  int idx = blockIdx.x * 256 + threadIdx.x;
  if (idx < 2048) {                                    // Ae_ih [k][j][g]
    int k = idx >> 8, j = (idx >> 2) & 63, g = idx & 3;
    p.ws[OFF_AE_IH + idx] = p.W_ih_e[(g * 64 + j) * 8 + k];
  } else if (idx < 2048 + 16384) {                     // Ae_hh [k][j][g]
    int i2 = idx - 2048;
    int k = i2 >> 8, j = (i2 >> 2) & 63, g = i2 & 3;
    p.ws[OFF_AE_HH + i2] = p.W_hh_e[(g * 64 + j) * 64 + k];
  } else if (idx < 2048 + 16384 + 32768) {             // Ad interleaved [k][j][8]: ih g then hh g
    int i2 = idx - (2048 + 16384);
    int k = i2 >> 9, j = (i2 >> 3) & 63, gg = i2 & 7;
    int g = gg & 3;
    const float* W = (gg < 4) ? p.W_ih_d : p.W_hh_d;
    p.ws[OFF_AD + i2] = W[(g * 64 + j) * 64 + k];
  } else if (idx < OFF_WOUT + 512) {                   // W_out_s[i][d][c] = W_out[d][c*8+i]
    int i2 = idx - OFF_WOUT;
    int i = i2 >> 6, d = (i2 >> 3) & 7, c = i2 & 7;
    p.ws[OFF_WOUT + i2] = p.W_out[d * 64 + c * 8 + i];
  } else if (idx < OFF_INP0 + 64) {                    // inp0 = start @ W_emb^T + b_emb
    int j = idx - OFF_INP0;
    float s = p.b_emb[j];
#pragma unroll
    for (int d = 0; d < 8; ++d) s += p.start[d] * p.W_emb[j * 8 + d];
    p.ws[OFF_INP0 + j] = s;
  } else if (idx < OFF_BE + 256) {
    int r = idx - OFF_BE;
    p.ws[OFF_BE + r] = p.b_ih_e[r] + p.b_hh_e[r];
  } else if (idx < OFF_BD + 256) {
    int r = idx - OFF_BD;
    p.ws[OFF_BD + r] = p.b_ih_d[r] + p.b_hh_d[r];
  }
}

// ---------------- encoder LSTM: 512 steps, write (hT, cT) to tmp ----------------
struct EncP {
  const float* x; const float* ws;
  float* tmp_h; float* tmp_c;
};

__global__ __launch_bounds__(256, 1) void enc_kernel(EncP p) {
  __shared__ float sAih[8 * 64 * 4];      // [k][j][g]
  __shared__ float sAhh[64 * 64 * 4];     // [k][j][g]
  __shared__ float sX[8 * 32 * 8];        // [seg][tt][d]
  int tid = threadIdx.x;
  {
    const float4* s1 = (const float4*)(p.ws + OFF_AE_IH);
    float4* d1 = (float4*)sAih;
    for (int i = tid; i < 512; i += 256) d1[i] = s1[i];
    const float4* s2 = (const float4*)(p.ws + OFF_AE_HH);
    float4* d2 = (float4*)sAhh;
    for (int i = tid; i < 4096; i += 256) d2[i] = s2[i];
  }
  __syncthreads();

  int wave = tid >> 6, lane = tid & 63;
  int b0 = blockIdx.x * 8 + wave * 2;          // this wave owns batches b0, b0+1
  const int w2 = wave * 2;

  float be0 = p.ws[OFF_BE + lane],       be1 = p.ws[OFF_BE + 64 + lane],
        be2 = p.ws[OFF_BE + 128 + lane], be3 = p.ws[OFF_BE + 192 + lane];

  float h_a = 0.f, h_b = 0.f, c_a = 0.f, c_b = 0.f;

  for (int tc = 0; tc < 16; ++tc) {
    // wave-private x staging: this wave's lanes load exactly its own 2 batches
    {
      int bs = lane >> 5, pos = lane & 31;
      const float* s = p.x + ((size_t)(b0 + bs) * T_ + tc * 32) * 8 + pos * 8;
      float4 v0 = *(const float4*)s;
      float4 v1 = *(const float4*)(s + 4);
      float* d = &sX[(w2 + bs) * 256 + pos * 8];
      *(float4*)d = v0;
      *(float4*)(d + 4) = v1;
    }
    for (int tt = 0; tt < 32; ++tt) {
      float4 xa0 = *(const float4*)&sX[w2 * 256 + tt * 8];
      float4 xa1 = *(const float4*)&sX[w2 * 256 + tt * 8 + 4];
      float4 xb0 = *(const float4*)&sX[(w2 + 1) * 256 + tt * 8];
      float4 xb1 = *(const float4*)&sX[(w2 + 1) * 256 + tt * 8 + 4];
      float xav[8] = {xa0.x, xa0.y, xa0.z, xa0.w, xa1.x, xa1.y, xa1.z, xa1.w};
      float xbv[8] = {xb0.x, xb0.y, xb0.z, xb0.w, xb1.x, xb1.y, xb1.z, xb1.w};

      float aia = be0, afa = be1, aga = be2, aoa = be3;
      float aib = be0, afb = be1, agb = be2, aob = be3;
#pragma unroll
      for (int k = 0; k < 8; ++k) {
        float4 w = *(const float4*)&sAih[(k * 64 + lane) * 4];
        aia = fmaf(w.x, xav[k], aia); afa = fmaf(w.y, xav[k], afa);
        aga = fmaf(w.z, xav[k], aga); aoa = fmaf(w.w, xav[k], aoa);
        aib = fmaf(w.x, xbv[k], aib); afb = fmaf(w.y, xbv[k], afb);
        agb = fmaf(w.z, xbv[k], agb); aob = fmaf(w.w, xbv[k], aob);
      }
#pragma unroll
      for (int k = 0; k < 64; ++k) {
        float4 w = *(const float4*)&sAhh[(k * 64 + lane) * 4];
        float ha = rdlane(h_a, k), hb = rdlane(h_b, k);
        aia = fmaf(w.x, ha, aia); afa = fmaf(w.y, ha, afa);
        aga = fmaf(w.z, ha, aga); aoa = fmaf(w.w, ha, aoa);
        aib = fmaf(w.x, hb, aib); afb = fmaf(w.y, hb, afb);
        agb = fmaf(w.z, hb, agb); aob = fmaf(w.w, hb, aob);
      }
      c_a = sigm(afa) * c_a + sigm(aia) * tanhf_(aga);
      h_a = sigm(aoa) * tanhf_(c_a);
      c_b = sigm(afb) * c_b + sigm(aib) * tanhf_(agb);
      h_b = sigm(aob) * tanhf_(c_b);
    }
  }

  p.tmp_h[b0 * H_ + lane]       = h_a;
  p.tmp_h[(b0 + 1) * H_ + lane] = h_b;
  p.tmp_c[b0 * H_ + lane]       = c_a;
  p.tmp_c[(b0 + 1) * H_ + lane] = c_b;
}

// ---------------- heads: mu/logvar/num/mass + decoder h0/c0 (one wave per batch) ----------------
struct HeadP {
  const float* tmp_h; const float* tmp_c;
  const float* W_mu; const float* b_mu; const float* W_lv; const float* b_lv;
  const float* W_l2h; const float* b_l2h; const float* W_l2h2; const float* b_l2h2;
  const float* W_seq; const float* b_seq; const float* W_seq2; const float* b_seq2;
  const float* W_m1; const float* b_m1; const float* W_m2; const float* b_m2;
  const float* W_m3; const float* b_m3;
  float* out_mu; float* out_lv; float* out_num; float* out_mass;
  float* ws_h0; float* ws_c0;
};

__global__ __launch_bounds__(256) void heads_kernel(HeadP p) {
  int tid = threadIdx.x;
  int wave = tid >> 6, lane = tid & 63;
  int b = blockIdx.x * 4 + wave;

  float hh = p.tmp_h[b * H_ + lane];
  float cc = p.tmp_c[b * H_ + lane];

  float muv = 0.f, lvv = 0.f;
#pragma unroll 1
  for (int l = 0; l < 16; ++l) {
    float pm = hh * p.W_mu[l * 128 + lane] + cc * p.W_mu[l * 128 + 64 + lane];
    float sm = wsum(pm);
    float pl = hh * p.W_lv[l * 128 + lane] + cc * p.W_lv[l * 128 + 64 + lane];
    float sl = wsum(pl);
    if (lane == l) { muv = sm + p.b_mu[l]; lvv = sl + p.b_lv[l]; }
  }
  if (lane < 16) {
    p.out_mu[b * L_ + lane] = muv;
    p.out_lv[b * L_ + lane] = lvv;
  }
  float mub[16];
#pragma unroll
  for (int l = 0; l < 16; ++l) mub[l] = __shfl(muv, l, 64);

  // decoder init h0/c0
  float s0 = p.b_l2h[lane], s1 = p.b_l2h2[lane];
#pragma unroll
  for (int l = 0; l < 16; ++l) {
    s0 = fmaf(mub[l], p.W_l2h[lane * 16 + l], s0);
    s1 = fmaf(mub[l], p.W_l2h2[lane * 16 + l], s1);
  }
  p.ws_h0[b * H_ + lane] = lrelu(s0);
  p.ws_c0[b * H_ + lane] = lrelu(s1);

  // num head
  float sn = p.b_seq[lane];
#pragma unroll
  for (int l = 0; l < 16; ++l) sn = fmaf(mub[l], p.W_seq[lane * 16 + l], sn);
  sn = lrelu(sn);
  float rn = wsum(sn * p.W_seq2[lane]) + p.b_seq2[0];
  if (lane == 0) p.out_num[b] = fmaxf(rn, 0.f);

  // mass head
  float m1 = p.b_m1[lane];
#pragma unroll
  for (int l = 0; l < 16; ++l) m1 = fmaf(mub[l], p.W_m1[lane * 16 + l], m1);
  m1 = lrelu(m1);
  float m2 = p.b_m2[lane];
#pragma unroll
  for (int k = 0; k < 64; ++k) m2 = fmaf(rdlane(m1, k), p.W_m2[lane * 64 + k], m2);
  m2 = lrelu(m2);
  float r0 = wsum(m2 * p.W_m3[lane]) + p.b_m3[0];
  float r1 = wsum(m2 * p.W_m3[64 + lane]) + p.b_m3[1];
  if (lane == 0) {
    float mx = fmaxf(r0, r1);
    float e0 = __expf(r0 - mx), e1 = __expf(r1 - mx);
    float inv = 1.0f / (e0 + e1);
    p.out_mass[b * P_ + 0] = e0 * inv;
    p.out_mass[b * P_ + 1] = e1 * inv;
  }
}

// ---------------- decoder: 512-step autoregressive LSTM + output proj ----------------
struct DecP {
  const float* ws; const float* b_out;
  float* out_recon;
};

__global__ __launch_bounds__(256, 1) void dec_kernel(DecP p) {
  __shared__ float sA[64 * 64 * 8];       // interleaved [k][j][ih.x..w | hh.x..w]
  __shared__ float sWout[512];            // [i][d][c]
  int tid = threadIdx.x;
  {
    const float4* s = (const float4*)(p.ws + OFF_AD);
    float4* d = (float4*)sA;
    for (int i = tid; i < 8192; i += 256) d[i] = s[i];
    for (int i = tid; i < 512; i += 256) sWout[i] = p.ws[OFF_WOUT + i];
  }
  __syncthreads();

  int wave = tid >> 6, lane = tid & 63;
  int b0 = blockIdx.x * 8 + wave * 2, b1 = b0 + 1;

  float bd0 = p.ws[OFF_BD + lane],       bd1 = p.ws[OFF_BD + 64 + lane],
        bd2 = p.ws[OFF_BD + 128 + lane], bd3 = p.ws[OFF_BD + 192 + lane];

  float hs_a = p.ws[OFF_H0 + b0 * H_ + lane], hs_b = p.ws[OFF_H0 + b1 * H_ + lane];
  float cs_a = p.ws[OFF_C0 + b0 * H_ + lane], cs_b = p.ws[OFF_C0 + b1 * H_ + lane];
  float rx_a = fmaxf(p.ws[OFF_INP0 + lane], 0.f);   // x_0 = relu(inp0)
  float rx_b = rx_a;

  int dd = lane & 7, cg = lane >> 3;
  float bod = p.b_out[dd];
  float* oa = p.out_recon + (size_t)b0 * T_ * D_;
  float* ob = p.out_recon + (size_t)b1 * T_ * D_;

  for (int t = 0; t < T_; ++t) {
    float aia = bd0, afa = bd1, aga = bd2, aoa = bd3;
    float aib = bd0, afb = bd1, agb = bd2, aob = bd3;
#pragma unroll
    for (int k = 0; k < 64; ++k) {
      float4 wi = *(const float4*)&sA[(k * 64 + lane) * 8];
      float4 wh = *(const float4*)&sA[(k * 64 + lane) * 8 + 4];
      float xa = rdlane(rx_a, k), ha = rdlane(hs_a, k);
      float xb = rdlane(rx_b, k), hb = rdlane(hs_b, k);
      aia = fmaf(wi.x, xa, aia); aia = fmaf(wh.x, ha, aia);
      afa = fmaf(wi.y, xa, afa); afa = fmaf(wh.y, ha, afa);
      aga = fmaf(wi.z, xa, aga); aga = fmaf(wh.z, ha, aga);
      aoa = fmaf(wi.w, xa, aoa); aoa = fmaf(wh.w, ha, aoa);
      aib = fmaf(wi.x, xb, aib); aib = fmaf(wh.x, hb, aib);
      afb = fmaf(wi.y, xb, afb); afb = fmaf(wh.y, hb, afb);
      agb = fmaf(wi.z, xb, agb); agb = fmaf(wh.z, hb, agb);
      aob = fmaf(wi.w, xb, aob); aob = fmaf(wh.w, hb, aob);
    }
    cs_a = sigm(afa) * cs_a + sigm(aia) * tanhf_(aga);
    float hn_a = sigm(aoa) * tanhf_(cs_a);
    cs_b = sigm(afb) * cs_b + sigm(aib) * tanhf_(agb);
    float hn_b = sigm(aob) * tanhf_(cs_b);

    // y = h_new @ W_out^T + b_out  (lane j: d = j&7, chunk cg = j>>3)
    float ya = 0.f, yb = 0.f;
#pragma unroll
    for (int i = 0; i < 8; ++i) {
      float w = sWout[i * 64 + dd * 8 + cg];
      ya = fmaf(w, __shfl(hn_a, cg * 8 + i, 64), ya);
      yb = fmaf(w, __shfl(hn_b, cg * 8 + i, 64), yb);
    }
    ya += __shfl_xor(ya, 8, 64); ya += __shfl_xor(ya, 16, 64); ya += __shfl_xor(ya, 32, 64);
    yb += __shfl_xor(yb, 8, 64); yb += __shfl_xor(yb, 16, 64); yb += __shfl_xor(yb, 32, 64);
    if (lane < 8) {
      oa[t * 8 + lane] = ya + bod;
      ob[t * 8 + lane] = yb + bod;
    }
    hs_a = hn_a; hs_b = hn_b;
    rx_a = fmaxf(hn_a, 0.f); rx_b = fmaxf(hn_b, 0.f);
  }
}

// ---------------- host ----------------
extern "C" void kernel_launch(void* const* d_in, const int* in_sizes, int n_in,
                              void* d_out, int out_size, void* d_ws, size_t ws_size,
                              hipStream_t stream) {
  const float* x       = (const float*)d_in[0];
  const float* start   = (const float*)d_in[1];
  const float* W_ih_e  = (const float*)d_in[2];
  const float* W_hh_e  = (const float*)d_in[3];
  const float* b_ih_e  = (const float*)d_in[4];
  const float* b_hh_e  = (const float*)d_in[5];
  const float* W_mu    = (const float*)d_in[6];
  const float* b_mu    = (const float*)d_in[7];
  const float* W_lv    = (const float*)d_in[8];
  const float* b_lv    = (const float*)d_in[9];
  const float* W_l2h   = (const float*)d_in[10];
  const float* b_l2h   = (const float*)d_in[11];
  const float* W_l2h2  = (const float*)d_in[12];
  const float* b_l2h2  = (const float*)d_in[13];
  const float* W_emb   = (const float*)d_in[14];
  const float* b_emb   = (const float*)d_in[15];
  const float* W_ih_d  = (const float*)d_in[16];
  const float* W_hh_d  = (const float*)d_in[17];
  const float* b_ih_d  = (const float*)d_in[18];
  const float* b_hh_d  = (const float*)d_in[19];
  const float* W_out   = (const float*)d_in[20];
  const float* b_out   = (const float*)d_in[21];
  const float* W_seq   = (const float*)d_in[22];
  const float* b_seq   = (const float*)d_in[23];
  const float* W_seq2  = (const float*)d_in[24];
  const float* b_seq2  = (const float*)d_in[25];
  const float* W_m1    = (const float*)d_in[26];
  const float* b_m1    = (const float*)d_in[27];
  const float* W_m2    = (const float*)d_in[28];
  const float* b_m2    = (const float*)d_in[29];
  const float* W_m3    = (const float*)d_in[30];
  const float* b_m3    = (const float*)d_in[31];

  float* ws  = (float*)d_ws;
  float* out = (float*)d_out;
  float* out_mu   = out + (size_t)B_ * T_ * D_;
  float* out_lv   = out_mu + B_ * L_;
  float* out_num  = out_lv + B_ * L_;
  float* out_mass = out_num + B_;

  // hT/cT scratch lives in the recon area of d_out (dec overwrites it afterwards)
  float* tmp_h = out;                   // B*H floats
  float* tmp_c = out + B_ * H_;         // B*H floats

  PrepP pp{W_ih_e, W_hh_e, b_ih_e, b_hh_e, W_ih_d, W_hh_d, b_ih_d, b_hh_d,
           W_out, start, W_emb, b_emb, ws};
  hipLaunchKernelGGL(prep_kernel, dim3(205), dim3(256), 0, stream, pp);

  EncP ep{x, ws, tmp_h, tmp_c};
  hipLaunchKernelGGL(enc_kernel, dim3(256), dim3(256), 0, stream, ep);

  HeadP hp{tmp_h, tmp_c, W_mu, b_mu, W_lv, b_lv, W_l2h, b_l2h, W_l2h2, b_l2h2,
           W_seq, b_seq, W_seq2, b_seq2, W_m1, b_m1, W_m2, b_m2, W_m3, b_m3,
           out_mu, out_lv, out_num, out_mass, ws + OFF_H0, ws + OFF_C0};
  hipLaunchKernelGGL(heads_kernel, dim3(512), dim3(256), 0, stream, hp);

  DecP dp{ws, b_out, out};
  hipLaunchKernelGGL(dec_kernel, dim3(256), dim3(256), 0, stream, dp);
}

// Round 3
// 5850.980 us; speedup vs baseline: 1.8768x; 1.8768x over previous
//
#include <hip/hip_runtime.h>
#include <math.h>

#define B_ 2048
#define T_ 512
#define D_ 8
#define H_ 64
#define L_ 16
#define P_ 2

// ---- workspace layout (float offsets) ----
#define OFF_AE_IH   0                       // [k=8][j=64][g=4]   = 2048
#define OFF_AE_HH   2048                    // [k=64][j=64][g=4]  = 16384
#define OFF_AD      18432                   // ih [k=64][j=64][g=4] then hh same = 32768
#define OFF_WOUT    51200                   // [i=8][d=8][c=8]    = 512
#define OFF_INP0    51712                   // 64
#define OFF_BE      51776                   // 256
#define OFF_BD      52032                   // 256
#define OFF_H0      52288                   // B*H
#define OFF_C0      (OFF_H0 + B_*H_)
#define WS_FLOATS   (OFF_C0 + B_*H_)

__device__ __forceinline__ float sigm(float x) { return 1.0f / (1.0f + __expf(-x)); }
__device__ __forceinline__ float tanhf_(float x) {
  float ax = fabsf(x);
  float e  = __expf(-2.0f * ax);
  float r  = (1.0f - e) / (1.0f + e);
  return copysignf(r, x);
}
__device__ __forceinline__ float lrelu(float x) { return x >= 0.0f ? x : 0.01f * x; }
__device__ __forceinline__ float rdlane(float v, int l) {
  return __int_as_float(__builtin_amdgcn_readlane(__float_as_int(v), l));
}
__device__ __forceinline__ float wsum(float v) {
#pragma unroll
  for (int off = 32; off > 0; off >>= 1) v += __shfl_xor(v, off, 64);
  return v;
}
// Opaque zero, re-materialized per call site: blocks LICM of LDS loads whose
// index includes it (compiler must assume it changes), costs one v_add.
__device__ __forceinline__ int opaque_zero() {
  int z = 0;
  asm volatile("" : "+v"(z));
  return z;
}

// ---------------- prep: repack weights / combine biases / start embedding ----------------
struct PrepP {
  const float* W_ih_e; const float* W_hh_e; const float* b_ih_e; const float* b_hh_e;
  const float* W_ih_d; const float* W_hh_d; const float* b_ih_d; const float* b_hh_d;
  const float* W_out;  const float* start;  const float* W_emb;  const float* b_emb;
  float* ws;
};

__global__ __launch_bounds__(256) void prep_kernel(PrepP p) {
  int idx = blockIdx.x * 256 + threadIdx.x;
  if (idx < 2048) {                                    // Ae_ih [k][j][g]
    int k = idx >> 8, j = (idx >> 2) & 63, g = idx & 3;
    p.ws[OFF_AE_IH + idx] = p.W_ih_e[(g * 64 + j) * 8 + k];
  } else if (idx < 2048 + 16384) {                     // Ae_hh [k][j][g]
    int i2 = idx - 2048;
    int k = i2 >> 8, j = (i2 >> 2) & 63, g = i2 & 3;
    p.ws[OFF_AE_HH + i2] = p.W_hh_e[(g * 64 + j) * 64 + k];
  } else if (idx < 2048 + 2 * 16384) {                 // Ad_ih [k][j][g]
    int i2 = idx - (2048 + 16384);
    int k = i2 >> 8, j = (i2 >> 2) & 63, g = i2 & 3;
    p.ws[OFF_AD + i2] = p.W_ih_d[(g * 64 + j) * 64 + k];
  } else if (idx < 2048 + 3 * 16384) {                 // Ad_hh [k][j][g]
    int i2 = idx - (2048 + 2 * 16384);
    int k = i2 >> 8, j = (i2 >> 2) & 63, g = i2 & 3;
    p.ws[OFF_AD + 16384 + i2] = p.W_hh_d[(g * 64 + j) * 64 + k];
  } else if (idx < OFF_WOUT + 512) {                   // W_out_s[i][d][c] = W_out[d][c*8+i]
    int i2 = idx - OFF_WOUT;
    int i = i2 >> 6, d = (i2 >> 3) & 7, c = i2 & 7;
    p.ws[OFF_WOUT + i2] = p.W_out[d * 64 + c * 8 + i];
  } else if (idx < OFF_INP0 + 64) {                    // inp0 = start @ W_emb^T + b_emb
    int j = idx - OFF_INP0;
    float s = p.b_emb[j];
#pragma unroll
    for (int d = 0; d < 8; ++d) s += p.start[d] * p.W_emb[j * 8 + d];
    p.ws[OFF_INP0 + j] = s;
  } else if (idx < OFF_BE + 256) {
    int r = idx - OFF_BE;
    p.ws[OFF_BE + r] = p.b_ih_e[r] + p.b_hh_e[r];
  } else if (idx < OFF_BD + 256) {
    int r = idx - OFF_BD;
    p.ws[OFF_BD + r] = p.b_ih_d[r] + p.b_hh_d[r];
  }
}

// ---------------- encoder LSTM: 512 steps, write (hT, cT) to tmp ----------------
struct EncP {
  const float* x; const float* ws;
  float* tmp_h; float* tmp_c;
};

__global__ __launch_bounds__(256, 1) void enc_kernel(EncP p) {
  __shared__ float sAih[8 * 64 * 4];      // [k][j][g]
  __shared__ float sAhh[64 * 64 * 4];     // [k][j][g]
  __shared__ float sX[8 * 32 * 8];        // [seg][tt][d]
  int tid = threadIdx.x;
  {
    const float4* s1 = (const float4*)(p.ws + OFF_AE_IH);
    float4* d1 = (float4*)sAih;
    for (int i = tid; i < 512; i += 256) d1[i] = s1[i];
    const float4* s2 = (const float4*)(p.ws + OFF_AE_HH);
    float4* d2 = (float4*)sAhh;
    for (int i = tid; i < 4096; i += 256) d2[i] = s2[i];
  }
  __syncthreads();

  int wave = tid >> 6, lane = tid & 63;
  int b0 = blockIdx.x * 8 + wave * 2;          // this wave owns batches b0, b0+1
  const int w2 = wave * 2;

  float be0 = p.ws[OFF_BE + lane],       be1 = p.ws[OFF_BE + 64 + lane],
        be2 = p.ws[OFF_BE + 128 + lane], be3 = p.ws[OFF_BE + 192 + lane];

  float h_a = 0.f, h_b = 0.f, c_a = 0.f, c_b = 0.f;

#pragma unroll 1
  for (int tc = 0; tc < 16; ++tc) {
    // wave-private x staging: this wave's lanes load exactly its own 2 batches
    {
      int bs = lane >> 5, pos = lane & 31;
      const float* s = p.x + ((size_t)(b0 + bs) * T_ + tc * 32) * 8 + pos * 8;
      float4 v0 = *(const float4*)s;
      float4 v1 = *(const float4*)(s + 4);
      float* d = &sX[(w2 + bs) * 256 + pos * 8];
      *(float4*)d = v0;
      *(float4*)(d + 4) = v1;
    }
#pragma unroll 1
    for (int tt = 0; tt < 32; ++tt) {
      int koff = opaque_zero();   // blocks LICM/hoist of weight loads out of tt
      float4 xa0 = *(const float4*)&sX[w2 * 256 + tt * 8];
      float4 xa1 = *(const float4*)&sX[w2 * 256 + tt * 8 + 4];
      float4 xb0 = *(const float4*)&sX[(w2 + 1) * 256 + tt * 8];
      float4 xb1 = *(const float4*)&sX[(w2 + 1) * 256 + tt * 8 + 4];
      float xav[8] = {xa0.x, xa0.y, xa0.z, xa0.w, xa1.x, xa1.y, xa1.z, xa1.w};
      float xbv[8] = {xb0.x, xb0.y, xb0.z, xb0.w, xb1.x, xb1.y, xb1.z, xb1.w};

      float aia = be0, afa = be1, aga = be2, aoa = be3;
      float aib = be0, afb = be1, agb = be2, aob = be3;
#pragma unroll
      for (int k = 0; k < 8; ++k) {        // small: hoisting 32 floats is fine
        float4 w = *(const float4*)&sAih[(k * 64 + lane) * 4];
        aia = fmaf(w.x, xav[k], aia); afa = fmaf(w.y, xav[k], afa);
        aga = fmaf(w.z, xav[k], aga); aoa = fmaf(w.w, xav[k], aoa);
        aib = fmaf(w.x, xbv[k], aib); afb = fmaf(w.y, xbv[k], afb);
        agb = fmaf(w.z, xbv[k], agb); aob = fmaf(w.w, xbv[k], aob);
      }
#pragma unroll 8
      for (int k = 0; k < 64; ++k) {       // partial unroll: loads stay in-loop
        float4 w = *(const float4*)&sAhh[(k * 64 + lane) * 4 + koff];
        float ha = rdlane(h_a, k), hb = rdlane(h_b, k);
        aia = fmaf(w.x, ha, aia); afa = fmaf(w.y, ha, afa);
        aga = fmaf(w.z, ha, aga); aoa = fmaf(w.w, ha, aoa);
        aib = fmaf(w.x, hb, aib); afb = fmaf(w.y, hb, afb);
        agb = fmaf(w.z, hb, agb); aob = fmaf(w.w, hb, aob);
      }
      c_a = sigm(afa) * c_a + sigm(aia) * tanhf_(aga);
      h_a = sigm(aoa) * tanhf_(c_a);
      c_b = sigm(afb) * c_b + sigm(aib) * tanhf_(agb);
      h_b = sigm(aob) * tanhf_(c_b);
    }
  }

  p.tmp_h[b0 * H_ + lane]       = h_a;
  p.tmp_h[(b0 + 1) * H_ + lane] = h_b;
  p.tmp_c[b0 * H_ + lane]       = c_a;
  p.tmp_c[(b0 + 1) * H_ + lane] = c_b;
}

// ---------------- heads: mu/logvar/num/mass + decoder h0/c0 (one wave per batch) ----------------
struct HeadP {
  const float* tmp_h; const float* tmp_c;
  const float* W_mu; const float* b_mu; const float* W_lv; const float* b_lv;
  const float* W_l2h; const float* b_l2h; const float* W_l2h2; const float* b_l2h2;
  const float* W_seq; const float* b_seq; const float* W_seq2; const float* b_seq2;
  const float* W_m1; const float* b_m1; const float* W_m2; const float* b_m2;
  const float* W_m3; const float* b_m3;
  float* out_mu; float* out_lv; float* out_num; float* out_mass;
  float* ws_h0; float* ws_c0;
};

__global__ __launch_bounds__(256) void heads_kernel(HeadP p) {
  int tid = threadIdx.x;
  int wave = tid >> 6, lane = tid & 63;
  int b = blockIdx.x * 4 + wave;

  float hh = p.tmp_h[b * H_ + lane];
  float cc = p.tmp_c[b * H_ + lane];

  float muv = 0.f, lvv = 0.f;
#pragma unroll 1
  for (int l = 0; l < 16; ++l) {
    float pm = hh * p.W_mu[l * 128 + lane] + cc * p.W_mu[l * 128 + 64 + lane];
    float sm = wsum(pm);
    float pl = hh * p.W_lv[l * 128 + lane] + cc * p.W_lv[l * 128 + 64 + lane];
    float sl = wsum(pl);
    if (lane == l) { muv = sm + p.b_mu[l]; lvv = sl + p.b_lv[l]; }
  }
  if (lane < 16) {
    p.out_mu[b * L_ + lane] = muv;
    p.out_lv[b * L_ + lane] = lvv;
  }
  float mub[16];
#pragma unroll
  for (int l = 0; l < 16; ++l) mub[l] = __shfl(muv, l, 64);

  // decoder init h0/c0
  float s0 = p.b_l2h[lane], s1 = p.b_l2h2[lane];
#pragma unroll
  for (int l = 0; l < 16; ++l) {
    s0 = fmaf(mub[l], p.W_l2h[lane * 16 + l], s0);
    s1 = fmaf(mub[l], p.W_l2h2[lane * 16 + l], s1);
  }
  p.ws_h0[b * H_ + lane] = lrelu(s0);
  p.ws_c0[b * H_ + lane] = lrelu(s1);

  // num head
  float sn = p.b_seq[lane];
#pragma unroll
  for (int l = 0; l < 16; ++l) sn = fmaf(mub[l], p.W_seq[lane * 16 + l], sn);
  sn = lrelu(sn);
  float rn = wsum(sn * p.W_seq2[lane]) + p.b_seq2[0];
  if (lane == 0) p.out_num[b] = fmaxf(rn, 0.f);

  // mass head
  float m1 = p.b_m1[lane];
#pragma unroll
  for (int l = 0; l < 16; ++l) m1 = fmaf(mub[l], p.W_m1[lane * 16 + l], m1);
  m1 = lrelu(m1);
  float m2 = p.b_m2[lane];
#pragma unroll
  for (int k = 0; k < 64; ++k) m2 = fmaf(rdlane(m1, k), p.W_m2[lane * 64 + k], m2);
  m2 = lrelu(m2);
  float r0 = wsum(m2 * p.W_m3[lane]) + p.b_m3[0];
  float r1 = wsum(m2 * p.W_m3[64 + lane]) + p.b_m3[1];
  if (lane == 0) {
    float mx = fmaxf(r0, r1);
    float e0 = __expf(r0 - mx), e1 = __expf(r1 - mx);
    float inv = 1.0f / (e0 + e1);
    p.out_mass[b * P_ + 0] = e0 * inv;
    p.out_mass[b * P_ + 1] = e1 * inv;
  }
}

// ---------------- decoder: 512-step autoregressive LSTM + output proj ----------------
struct DecP {
  const float* ws; const float* b_out;
  float* out_recon;
};

__global__ __launch_bounds__(256, 1) void dec_kernel(DecP p) {
  __shared__ float sAi[64 * 64 * 4];      // ih [k][j][g]
  __shared__ float sAh[64 * 64 * 4];      // hh [k][j][g]
  __shared__ float sWout[512];            // [i][d][c]
  int tid = threadIdx.x;
  {
    const float4* s = (const float4*)(p.ws + OFF_AD);
    float4* di = (float4*)sAi;
    float4* dh = (float4*)sAh;
    for (int i = tid; i < 4096; i += 256) di[i] = s[i];
    for (int i = tid; i < 4096; i += 256) dh[i] = s[4096 + i];
    for (int i = tid; i < 512; i += 256) sWout[i] = p.ws[OFF_WOUT + i];
  }
  __syncthreads();

  int wave = tid >> 6, lane = tid & 63;
  int b0 = blockIdx.x * 8 + wave * 2, b1 = b0 + 1;

  float bd0 = p.ws[OFF_BD + lane],       bd1 = p.ws[OFF_BD + 64 + lane],
        bd2 = p.ws[OFF_BD + 128 + lane], bd3 = p.ws[OFF_BD + 192 + lane];

  float hs_a = p.ws[OFF_H0 + b0 * H_ + lane], hs_b = p.ws[OFF_H0 + b1 * H_ + lane];
  float cs_a = p.ws[OFF_C0 + b0 * H_ + lane], cs_b = p.ws[OFF_C0 + b1 * H_ + lane];
  float rx_a = fmaxf(p.ws[OFF_INP0 + lane], 0.f);   // x_0 = relu(inp0)
  float rx_b = rx_a;

  int dd = lane & 7, cg = lane >> 3;
  float bod = p.b_out[dd];
  float* oa = p.out_recon + (size_t)b0 * T_ * D_;
  float* ob = p.out_recon + (size_t)b1 * T_ * D_;

#pragma unroll 1
  for (int t = 0; t < T_; ++t) {
    int koff = opaque_zero();   // blocks LICM/hoist of weight loads out of t
    float aia = bd0, afa = bd1, aga = bd2, aoa = bd3;
    float aib = bd0, afb = bd1, agb = bd2, aob = bd3;
#pragma unroll 8
    for (int k = 0; k < 64; ++k) {
      float4 wi = *(const float4*)&sAi[(k * 64 + lane) * 4 + koff];
      float4 wh = *(const float4*)&sAh[(k * 64 + lane) * 4 + koff];
      float xa = rdlane(rx_a, k), ha = rdlane(hs_a, k);
      float xb = rdlane(rx_b, k), hb = rdlane(hs_b, k);
      aia = fmaf(wi.x, xa, aia); aia = fmaf(wh.x, ha, aia);
      afa = fmaf(wi.y, xa, afa); afa = fmaf(wh.y, ha, afa);
      aga = fmaf(wi.z, xa, aga); aga = fmaf(wh.z, ha, aga);
      aoa = fmaf(wi.w, xa, aoa); aoa = fmaf(wh.w, ha, aoa);
      aib = fmaf(wi.x, xb, aib); aib = fmaf(wh.x, hb, aib);
      afb = fmaf(wi.y, xb, afb); afb = fmaf(wh.y, hb, afb);
      agb = fmaf(wi.z, xb, agb); agb = fmaf(wh.z, hb, agb);
      aob = fmaf(wi.w, xb, aob); aob = fmaf(wh.w, hb, aob);
    }
    cs_a = sigm(afa) * cs_a + sigm(aia) * tanhf_(aga);
    float hn_a = sigm(aoa) * tanhf_(cs_a);
    cs_b = sigm(afb) * cs_b + sigm(aib) * tanhf_(agb);
    float hn_b = sigm(aob) * tanhf_(cs_b);

    // y = h_new @ W_out^T + b_out  (lane j: d = j&7, chunk cg = j>>3)
    float ya = 0.f, yb = 0.f;
#pragma unroll
    for (int i = 0; i < 8; ++i) {
      float w = sWout[i * 64 + dd * 8 + cg];
      ya = fmaf(w, __shfl(hn_a, cg * 8 + i, 64), ya);
      yb = fmaf(w, __shfl(hn_b, cg * 8 + i, 64), yb);
    }
    ya += __shfl_xor(ya, 8, 64); ya += __shfl_xor(ya, 16, 64); ya += __shfl_xor(ya, 32, 64);
    yb += __shfl_xor(yb, 8, 64); yb += __shfl_xor(yb, 16, 64); yb += __shfl_xor(yb, 32, 64);
    if (lane < 8) {
      oa[t * 8 + lane] = ya + bod;
      ob[t * 8 + lane] = yb + bod;
    }
    hs_a = hn_a; hs_b = hn_b;
    rx_a = fmaxf(hn_a, 0.f); rx_b = fmaxf(hn_b, 0.f);
  }
}

// ---------------- host ----------------
extern "C" void kernel_launch(void* const* d_in, const int* in_sizes, int n_in,
                              void* d_out, int out_size, void* d_ws, size_t ws_size,
                              hipStream_t stream) {
  const float* x       = (const float*)d_in[0];
  const float* start   = (const float*)d_in[1];
  const float* W_ih_e  = (const float*)d_in[2];
  const float* W_hh_e  = (const float*)d_in[3];
  const float* b_ih_e  = (const float*)d_in[4];
  const float* b_hh_e  = (const float*)d_in[5];
  const float* W_mu    = (const float*)d_in[6];
  const float* b_mu    = (const float*)d_in[7];
  const float* W_lv    = (const float*)d_in[8];
  const float* b_lv    = (const float*)d_in[9];
  const float* W_l2h   = (const float*)d_in[10];
  const float* b_l2h   = (const float*)d_in[11];
  const float* W_l2h2  = (const float*)d_in[12];
  const float* b_l2h2  = (const float*)d_in[13];
  const float* W_emb   = (const float*)d_in[14];
  const float* b_emb   = (const float*)d_in[15];
  const float* W_ih_d  = (const float*)d_in[16];
  const float* W_hh_d  = (const float*)d_in[17];
  const float* b_ih_d  = (const float*)d_in[18];
  const float* b_hh_d  = (const float*)d_in[19];
  const float* W_out   = (const float*)d_in[20];
  const float* b_out   = (const float*)d_in[21];
  const float* W_seq   = (const float*)d_in[22];
  const float* b_seq   = (const float*)d_in[23];
  const float* W_seq2  = (const float*)d_in[24];
  const float* b_seq2  = (const float*)d_in[25];
  const float* W_m1    = (const float*)d_in[26];
  const float* b_m1    = (const float*)d_in[27];
  const float* W_m2    = (const float*)d_in[28];
  const float* b_m2    = (const float*)d_in[29];
  const float* W_m3    = (const float*)d_in[30];
  const float* b_m3    = (const float*)d_in[31];

  float* ws  = (float*)d_ws;
  float* out = (float*)d_out;
  float* out_mu   = out + (size_t)B_ * T_ * D_;
  float* out_lv   = out_mu + B_ * L_;
  float* out_num  = out_lv + B_ * L_;
  float* out_mass = out_num + B_;

  // hT/cT scratch lives in the recon area of d_out (dec overwrites it afterwards)
  float* tmp_h = out;                   // B*H floats
  float* tmp_c = out + B_ * H_;         // B*H floats

  PrepP pp{W_ih_e, W_hh_e, b_ih_e, b_hh_e, W_ih_d, W_hh_d, b_ih_d, b_hh_d,
           W_out, start, W_emb, b_emb, ws};
  hipLaunchKernelGGL(prep_kernel, dim3(205), dim3(256), 0, stream, pp);

  EncP ep{x, ws, tmp_h, tmp_c};
  hipLaunchKernelGGL(enc_kernel, dim3(256), dim3(256), 0, stream, ep);

  HeadP hp{tmp_h, tmp_c, W_mu, b_mu, W_lv, b_lv, W_l2h, b_l2h, W_l2h2, b_l2h2,
           W_seq, b_seq, W_seq2, b_seq2, W_m1, b_m1, W_m2, b_m2, W_m3, b_m3,
           out_mu, out_lv, out_num, out_mass, ws + OFF_H0, ws + OFF_C0};
  hipLaunchKernelGGL(heads_kernel, dim3(512), dim3(256), 0, stream, hp);

  DecP dp{ws, b_out, out};
  hipLaunchKernelGGL(dec_kernel, dim3(256), dim3(256), 0, stream, dp);
}

// Round 5
// 2191.541 us; speedup vs baseline: 5.0107x; 2.6698x over previous
//
#include <hip/hip_runtime.h>
#include <math.h>

#define B_ 2048
#define T_ 512
#define D_ 8
#define H_ 64
#define L_ 16
#define P_ 2

// ---- workspace layout (float offsets) ----
#define OFF_AE_IH   0                       // [k=8][j=64][g=4]   = 2048
#define OFF_AE_HH   2048                    // [k=64][j=64][g=4]  = 16384
#define OFF_AD      18432                   // ih [k=64][j=64][g=4] then hh same = 32768
#define OFF_WOUT    51200                   // [i=8][d=8][c=8]    = 512
#define OFF_INP0    51712                   // 64
#define OFF_BE      51776                   // 256
#define OFF_BD      52032                   // 256
#define OFF_H0      52288                   // B*H
#define OFF_C0      (OFF_H0 + B_*H_)

__device__ __forceinline__ float sigm(float x) { return 1.0f / (1.0f + __expf(-x)); }
__device__ __forceinline__ float tanhf_(float x) {
  float ax = fabsf(x);
  float e  = __expf(-2.0f * ax);
  float r  = (1.0f - e) / (1.0f + e);
  return copysignf(r, x);
}
__device__ __forceinline__ float lrelu(float x) { return x >= 0.0f ? x : 0.01f * x; }
__device__ __forceinline__ float rdlane(float v, int l) {
  return __int_as_float(__builtin_amdgcn_readlane(__float_as_int(v), l));
}
__device__ __forceinline__ float wsum(float v) {
#pragma unroll
  for (int off = 32; off > 0; off >>= 1) v += __shfl_xor(v, off, 64);
  return v;
}

// ---------------- prep: repack weights / combine biases / start embedding ----------------
struct PrepP {
  const float* W_ih_e; const float* W_hh_e; const float* b_ih_e; const float* b_hh_e;
  const float* W_ih_d; const float* W_hh_d; const float* b_ih_d; const float* b_hh_d;
  const float* W_out;  const float* start;  const float* W_emb;  const float* b_emb;
  float* ws;
};

__global__ __launch_bounds__(256) void prep_kernel(PrepP p) {
  int idx = blockIdx.x * 256 + threadIdx.x;
  if (idx < 2048) {                                    // Ae_ih [k][j][g]
    int k = idx >> 8, j = (idx >> 2) & 63, g = idx & 3;
    p.ws[OFF_AE_IH + idx] = p.W_ih_e[(g * 64 + j) * 8 + k];
  } else if (idx < 2048 + 16384) {                     // Ae_hh [k][j][g]
    int i2 = idx - 2048;
    int k = i2 >> 8, j = (i2 >> 2) & 63, g = i2 & 3;
    p.ws[OFF_AE_HH + i2] = p.W_hh_e[(g * 64 + j) * 64 + k];
  } else if (idx < 2048 + 2 * 16384) {                 // Ad_ih [k][j][g]
    int i2 = idx - (2048 + 16384);
    int k = i2 >> 8, j = (i2 >> 2) & 63, g = i2 & 3;
    p.ws[OFF_AD + i2] = p.W_ih_d[(g * 64 + j) * 64 + k];
  } else if (idx < 2048 + 3 * 16384) {                 // Ad_hh [k][j][g]
    int i2 = idx - (2048 + 2 * 16384);
    int k = i2 >> 8, j = (i2 >> 2) & 63, g = i2 & 3;
    p.ws[OFF_AD + 16384 + i2] = p.W_hh_d[(g * 64 + j) * 64 + k];
  } else if (idx < OFF_WOUT + 512) {                   // W_out_s[i][d][c] = W_out[d][c*8+i]
    int i2 = idx - OFF_WOUT;
    int i = i2 >> 6, d = (i2 >> 3) & 7, c = i2 & 7;
    p.ws[OFF_WOUT + i2] = p.W_out[d * 64 + c * 8 + i];
  } else if (idx < OFF_INP0 + 64) {                    // inp0 = start @ W_emb^T + b_emb
    int j = idx - OFF_INP0;
    float s = p.b_emb[j];
#pragma unroll
    for (int d = 0; d < 8; ++d) s += p.start[d] * p.W_emb[j * 8 + d];
    p.ws[OFF_INP0 + j] = s;
  } else if (idx < OFF_BE + 256) {
    int r = idx - OFF_BE;
    p.ws[OFF_BE + r] = p.b_ih_e[r] + p.b_hh_e[r];
  } else if (idx < OFF_BD + 256) {
    int r = idx - OFF_BD;
    p.ws[OFF_BD + r] = p.b_ih_d[r] + p.b_hh_d[r];
  }
}

// ---------------- encoder: split-K-8, 8 waves, 8 batches per block ----------------
// wave w holds W_hh rows k in [8w,8w+8) in registers; computes partial gates for
// all 8 batches; partials combined in LDS; wave b finalizes batch b.
struct EncP {
  const float* x; const float* ws;
  float* tmp_h; float* tmp_c;
};

__global__ __launch_bounds__(512, 1) void enc_kernel(EncP p) {
  __shared__ float4 part[8 * 8 * 64];     // [w][b][j]  64 KB
  __shared__ float  h_buf[8 * 68];        // [b][j] padded stride 68
  __shared__ float  sX[8][32][8];         // per-wave x chunk

  int tid = threadIdx.x;
  int wave = tid >> 6, lane = tid & 63;
  int ks = wave * 8;
  int bmine = blockIdx.x * 8 + wave;

  // weights in registers
  float4 wih[8], whh[8];
#pragma unroll
  for (int kk = 0; kk < 8; ++kk) {
    wih[kk] = *(const float4*)(p.ws + OFF_AE_IH + (size_t)(kk * 64 + lane) * 4);
    whh[kk] = *(const float4*)(p.ws + OFF_AE_HH + (size_t)((ks + kk) * 64 + lane) * 4);
  }
  float4 be = make_float4(p.ws[OFF_BE + lane], p.ws[OFF_BE + 64 + lane],
                          p.ws[OFF_BE + 128 + lane], p.ws[OFF_BE + 192 + lane]);

  float c = 0.f, hcur = 0.f;
  float vh = 0.f;                          // gathered h[b][ks+kk] for lane = b*8+kk

#pragma unroll 1
  for (int tc = 0; tc < 16; ++tc) {
    // stage this wave's batch x chunk: 32 steps x 8 dims = 256 floats
    {
      int tl = lane >> 1, half = lane & 1;
      const float* s = p.x + ((size_t)bmine * T_ + tc * 32 + tl) * 8 + half * 4;
      *(float4*)&sX[wave][tl][half * 4] = *(const float4*)s;
    }
#pragma unroll 1
    for (int tt = 0; tt < 32; ++tt) {
      float4 xlo = *(const float4*)&sX[wave][tt][0];
      float4 xhi = *(const float4*)&sX[wave][tt][4];

      float4 acc[8];
#pragma unroll
      for (int b = 0; b < 8; ++b) acc[b] = make_float4(0.f, 0.f, 0.f, 0.f);
#pragma unroll
      for (int kk = 0; kk < 8; ++kk) {
#pragma unroll
        for (int b = 0; b < 8; ++b) {
          float s = rdlane(vh, b * 8 + kk);
          acc[b].x = fmaf(whh[kk].x, s, acc[b].x);
          acc[b].y = fmaf(whh[kk].y, s, acc[b].y);
          acc[b].z = fmaf(whh[kk].z, s, acc[b].z);
          acc[b].w = fmaf(whh[kk].w, s, acc[b].w);
        }
      }
#pragma unroll
      for (int b = 0; b < 8; ++b) part[(wave * 8 + b) * 64 + lane] = acc[b];
      __syncthreads();

      // finalize own batch: bias + ih(x) + sum of 8 partials
      float4 g = be;
      float xv[8] = {xlo.x, xlo.y, xlo.z, xlo.w, xhi.x, xhi.y, xhi.z, xhi.w};
#pragma unroll
      for (int k = 0; k < 8; ++k) {
        g.x = fmaf(wih[k].x, xv[k], g.x);
        g.y = fmaf(wih[k].y, xv[k], g.y);
        g.z = fmaf(wih[k].z, xv[k], g.z);
        g.w = fmaf(wih[k].w, xv[k], g.w);
      }
#pragma unroll
      for (int w = 0; w < 8; ++w) {
        float4 pw = part[(w * 8 + wave) * 64 + lane];
        g.x += pw.x; g.y += pw.y; g.z += pw.z; g.w += pw.w;
      }
      c = sigm(g.y) * c + sigm(g.x) * tanhf_(g.z);
      hcur = sigm(g.w) * tanhf_(c);

      h_buf[wave * 68 + lane] = hcur;
      __syncthreads();
      vh = h_buf[(lane >> 3) * 68 + ks + (lane & 7)];
    }
  }

  p.tmp_h[bmine * H_ + lane] = hcur;
  p.tmp_c[bmine * H_ + lane] = c;
}

// ---------------- heads: mu/logvar/num/mass + decoder h0/c0 (one wave per batch) ----------------
struct HeadP {
  const float* tmp_h; const float* tmp_c;
  const float* W_mu; const float* b_mu; const float* W_lv; const float* b_lv;
  const float* W_l2h; const float* b_l2h; const float* W_l2h2; const float* b_l2h2;
  const float* W_seq; const float* b_seq; const float* W_seq2; const float* b_seq2;
  const float* W_m1; const float* b_m1; const float* W_m2; const float* b_m2;
  const float* W_m3; const float* b_m3;
  float* out_mu; float* out_lv; float* out_num; float* out_mass;
  float* ws_h0; float* ws_c0;
};

__global__ __launch_bounds__(256) void heads_kernel(HeadP p) {
  int tid = threadIdx.x;
  int wave = tid >> 6, lane = tid & 63;
  int b = blockIdx.x * 4 + wave;

  float hh = p.tmp_h[b * H_ + lane];
  float cc = p.tmp_c[b * H_ + lane];

  float muv = 0.f, lvv = 0.f;
#pragma unroll 1
  for (int l = 0; l < 16; ++l) {
    float pm = hh * p.W_mu[l * 128 + lane] + cc * p.W_mu[l * 128 + 64 + lane];
    float sm = wsum(pm);
    float pl = hh * p.W_lv[l * 128 + lane] + cc * p.W_lv[l * 128 + 64 + lane];
    float sl = wsum(pl);
    if (lane == l) { muv = sm + p.b_mu[l]; lvv = sl + p.b_lv[l]; }
  }
  if (lane < 16) {
    p.out_mu[b * L_ + lane] = muv;
    p.out_lv[b * L_ + lane] = lvv;
  }
  float mub[16];
#pragma unroll
  for (int l = 0; l < 16; ++l) mub[l] = __shfl(muv, l, 64);

  float s0 = p.b_l2h[lane], s1 = p.b_l2h2[lane];
#pragma unroll
  for (int l = 0; l < 16; ++l) {
    s0 = fmaf(mub[l], p.W_l2h[lane * 16 + l], s0);
    s1 = fmaf(mub[l], p.W_l2h2[lane * 16 + l], s1);
  }
  p.ws_h0[b * H_ + lane] = lrelu(s0);
  p.ws_c0[b * H_ + lane] = lrelu(s1);

  float sn = p.b_seq[lane];
#pragma unroll
  for (int l = 0; l < 16; ++l) sn = fmaf(mub[l], p.W_seq[lane * 16 + l], sn);
  sn = lrelu(sn);
  float rn = wsum(sn * p.W_seq2[lane]) + p.b_seq2[0];
  if (lane == 0) p.out_num[b] = fmaxf(rn, 0.f);

  float m1 = p.b_m1[lane];
#pragma unroll
  for (int l = 0; l < 16; ++l) m1 = fmaf(mub[l], p.W_m1[lane * 16 + l], m1);
  m1 = lrelu(m1);
  float m2 = p.b_m2[lane];
#pragma unroll
  for (int k = 0; k < 64; ++k) m2 = fmaf(rdlane(m1, k), p.W_m2[lane * 64 + k], m2);
  m2 = lrelu(m2);
  float r0 = wsum(m2 * p.W_m3[lane]) + p.b_m3[0];
  float r1 = wsum(m2 * p.W_m3[64 + lane]) + p.b_m3[1];
  if (lane == 0) {
    float mx = fmaxf(r0, r1);
    float e0 = __expf(r0 - mx), e1 = __expf(r1 - mx);
    float inv = 1.0f / (e0 + e1);
    p.out_mass[b * P_ + 0] = e0 * inv;
    p.out_mass[b * P_ + 1] = e1 * inv;
  }
}

// ---------------- decoder: split-K-8, weights in registers ----------------
struct DecP {
  const float* ws; const float* b_out;
  float* out_recon;
};

__global__ __launch_bounds__(512, 1) void dec_kernel(DecP p) {
  __shared__ float4 part[8 * 8 * 64];     // [w][b][j]  64 KB
  __shared__ float  h_buf[8 * 68];        // [b][j] padded stride 68
  __shared__ float  sWout[512];

  int tid = threadIdx.x;
  int wave = tid >> 6, lane = tid & 63;
  int ks = wave * 8;
  int bmine = blockIdx.x * 8 + wave;

  sWout[tid] = p.ws[OFF_WOUT + tid];

  float4 wih[8], whh[8];
#pragma unroll
  for (int kk = 0; kk < 8; ++kk) {
    wih[kk] = *(const float4*)(p.ws + OFF_AD + (size_t)((ks + kk) * 64 + lane) * 4);
    whh[kk] = *(const float4*)(p.ws + OFF_AD + 16384 + (size_t)((ks + kk) * 64 + lane) * 4);
  }
  float4 bd = make_float4(p.ws[OFF_BD + lane], p.ws[OFF_BD + 64 + lane],
                          p.ws[OFF_BD + 128 + lane], p.ws[OFF_BD + 192 + lane]);

  float c = p.ws[OFF_C0 + bmine * H_ + lane];
  h_buf[wave * 68 + lane] = p.ws[OFF_H0 + bmine * H_ + lane];
  float vx = fmaxf(p.ws[OFF_INP0 + ks + (lane & 7)], 0.f);  // x_0 same for all batches
  __syncthreads();
  float vh = h_buf[(lane >> 3) * 68 + ks + (lane & 7)];

  int dd = lane & 7, cg = lane >> 3;
  float bod = p.b_out[dd];
  float* om = p.out_recon + (size_t)bmine * T_ * D_;

#pragma unroll 1
  for (int t = 0; t < T_; ++t) {
    float4 acc[8];
#pragma unroll
    for (int b = 0; b < 8; ++b) acc[b] = make_float4(0.f, 0.f, 0.f, 0.f);
#pragma unroll
    for (int kk = 0; kk < 8; ++kk) {
#pragma unroll
      for (int b = 0; b < 8; ++b) {
        float s = rdlane(vh, b * 8 + kk);
        float r = rdlane(vx, b * 8 + kk);
        acc[b].x = fmaf(wih[kk].x, r, acc[b].x);
        acc[b].y = fmaf(wih[kk].y, r, acc[b].y);
        acc[b].z = fmaf(wih[kk].z, r, acc[b].z);
        acc[b].w = fmaf(wih[kk].w, r, acc[b].w);
        acc[b].x = fmaf(whh[kk].x, s, acc[b].x);
        acc[b].y = fmaf(whh[kk].y, s, acc[b].y);
        acc[b].z = fmaf(whh[kk].z, s, acc[b].z);
        acc[b].w = fmaf(whh[kk].w, s, acc[b].w);
      }
    }
#pragma unroll
    for (int b = 0; b < 8; ++b) part[(wave * 8 + b) * 64 + lane] = acc[b];
    __syncthreads();

    float4 g = bd;
#pragma unroll
    for (int w = 0; w < 8; ++w) {
      float4 pw = part[(w * 8 + wave) * 64 + lane];
      g.x += pw.x; g.y += pw.y; g.z += pw.z; g.w += pw.w;
    }
    c = sigm(g.y) * c + sigm(g.x) * tanhf_(g.z);
    float h = sigm(g.w) * tanhf_(c);

    // y = h @ W_out^T + b_out for own batch
    float y = 0.f;
#pragma unroll
    for (int i = 0; i < 8; ++i)
      y = fmaf(sWout[i * 64 + dd * 8 + cg], __shfl(h, cg * 8 + i, 64), y);
    y += __shfl_xor(y, 8, 64); y += __shfl_xor(y, 16, 64); y += __shfl_xor(y, 32, 64);
    if (lane < 8) om[t * 8 + lane] = y + bod;

    h_buf[wave * 68 + lane] = h;
    __syncthreads();
    vh = h_buf[(lane >> 3) * 68 + ks + (lane & 7)];
    vx = fmaxf(vh, 0.f);
  }
}

// ---------------- host ----------------
extern "C" void kernel_launch(void* const* d_in, const int* in_sizes, int n_in,
                              void* d_out, int out_size, void* d_ws, size_t ws_size,
                              hipStream_t stream) {
  const float* x       = (const float*)d_in[0];
  const float* start   = (const float*)d_in[1];
  const float* W_ih_e  = (const float*)d_in[2];
  const float* W_hh_e  = (const float*)d_in[3];
  const float* b_ih_e  = (const float*)d_in[4];
  const float* b_hh_e  = (const float*)d_in[5];
  const float* W_mu    = (const float*)d_in[6];
  const float* b_mu    = (const float*)d_in[7];
  const float* W_lv    = (const float*)d_in[8];
  const float* b_lv    = (const float*)d_in[9];
  const float* W_l2h   = (const float*)d_in[10];
  const float* b_l2h   = (const float*)d_in[11];
  const float* W_l2h2  = (const float*)d_in[12];
  const float* b_l2h2  = (const float*)d_in[13];
  const float* W_emb   = (const float*)d_in[14];
  const float* b_emb   = (const float*)d_in[15];
  const float* W_ih_d  = (const float*)d_in[16];
  const float* W_hh_d  = (const float*)d_in[17];
  const float* b_ih_d  = (const float*)d_in[18];
  const float* b_hh_d  = (const float*)d_in[19];
  const float* W_out   = (const float*)d_in[20];
  const float* b_out   = (const float*)d_in[21];
  const float* W_seq   = (const float*)d_in[22];
  const float* b_seq   = (const float*)d_in[23];
  const float* W_seq2  = (const float*)d_in[24];
  const float* b_seq2  = (const float*)d_in[25];
  const float* W_m1    = (const float*)d_in[26];
  const float* b_m1    = (const float*)d_in[27];
  const float* W_m2    = (const float*)d_in[28];
  const float* b_m2    = (const float*)d_in[29];
  const float* W_m3    = (const float*)d_in[30];
  const float* b_m3    = (const float*)d_in[31];

  float* ws  = (float*)d_ws;
  float* out = (float*)d_out;
  float* out_mu   = out + (size_t)B_ * T_ * D_;
  float* out_lv   = out_mu + B_ * L_;
  float* out_num  = out_lv + B_ * L_;
  float* out_mass = out_num + B_;

  // hT/cT scratch lives in the recon area of d_out (dec overwrites it afterwards)
  float* tmp_h = out;                   // B*H floats
  float* tmp_c = out + B_ * H_;         // B*H floats

  PrepP pp{W_ih_e, W_hh_e, b_ih_e, b_hh_e, W_ih_d, W_hh_d, b_ih_d, b_hh_d,
           W_out, start, W_emb, b_emb, ws};
  hipLaunchKernelGGL(prep_kernel, dim3(205), dim3(256), 0, stream, pp);

  EncP ep{x, ws, tmp_h, tmp_c};
  hipLaunchKernelGGL(enc_kernel, dim3(256), dim3(512), 0, stream, ep);

  HeadP hp{tmp_h, tmp_c, W_mu, b_mu, W_lv, b_lv, W_l2h, b_l2h, W_l2h2, b_l2h2,
           W_seq, b_seq, W_seq2, b_seq2, W_m1, b_m1, W_m2, b_m2, W_m3, b_m3,
           out_mu, out_lv, out_num, out_mass, ws + OFF_H0, ws + OFF_C0};
  hipLaunchKernelGGL(heads_kernel, dim3(512), dim3(256), 0, stream, hp);

  DecP dp{ws, b_out, out};
  hipLaunchKernelGGL(dec_kernel, dim3(256), dim3(512), 0, stream, dp);
}

// Round 6
// 2061.460 us; speedup vs baseline: 5.3269x; 1.0631x over previous
//
#include <hip/hip_runtime.h>
#include <math.h>

#define B_ 2048
#define T_ 512
#define D_ 8
#define H_ 64
#define L_ 16
#define P_ 2

// ---- workspace layout (float offsets) ----
#define OFF_AE_IH   0                       // [k=8][j=64][g=4]   = 2048
#define OFF_AE_HH   2048                    // [k=64][j=64][g=4]  = 16384
#define OFF_AD      18432                   // Wa [k][j][g] (16384) then Wb [k][j][g] (16384)
#define OFF_WOUT    51200                   // [i=8][d=8][c=8]    = 512
#define OFF_INP0    51712                   // 64
#define OFF_BE      51776                   // 256
#define OFF_BD      52032                   // 256
#define OFF_H0      52288                   // B*H
#define OFF_C0      (OFF_H0 + B_*H_)

__device__ __forceinline__ float sigm(float x) { return 1.0f / (1.0f + __expf(-x)); }
__device__ __forceinline__ float tanhf_(float x) {
  float ax = fabsf(x);
  float e  = __expf(-2.0f * ax);
  float r  = (1.0f - e) / (1.0f + e);
  return copysignf(r, x);
}
__device__ __forceinline__ float lrelu(float x) { return x >= 0.0f ? x : 0.01f * x; }
__device__ __forceinline__ float rdlane(float v, int l) {
  return __int_as_float(__builtin_amdgcn_readlane(__float_as_int(v), l));
}
__device__ __forceinline__ float wsum(float v) {
#pragma unroll
  for (int off = 32; off > 0; off >>= 1) v += __shfl_xor(v, off, 64);
  return v;
}

// ---------------- prep: repack weights / combine biases / start embedding ----------------
// Decoder weights are stored as Wa = W_hh + 0.5*W_ih, Wb = 0.5*W_ih so that
// gates = Wa*h + Wb*|h|  ==  W_hh*h + W_ih*relu(h)   (decoder input = relu(prev h)).
struct PrepP {
  const float* W_ih_e; const float* W_hh_e; const float* b_ih_e; const float* b_hh_e;
  const float* W_ih_d; const float* W_hh_d; const float* b_ih_d; const float* b_hh_d;
  const float* W_out;  const float* start;  const float* W_emb;  const float* b_emb;
  float* ws;
};

__global__ __launch_bounds__(256) void prep_kernel(PrepP p) {
  int idx = blockIdx.x * 256 + threadIdx.x;
  if (idx < 2048) {                                    // Ae_ih [k][j][g]
    int k = idx >> 8, j = (idx >> 2) & 63, g = idx & 3;
    p.ws[OFF_AE_IH + idx] = p.W_ih_e[(g * 64 + j) * 8 + k];
  } else if (idx < 2048 + 16384) {                     // Ae_hh [k][j][g]
    int i2 = idx - 2048;
    int k = i2 >> 8, j = (i2 >> 2) & 63, g = i2 & 3;
    p.ws[OFF_AE_HH + i2] = p.W_hh_e[(g * 64 + j) * 64 + k];
  } else if (idx < 2048 + 2 * 16384) {                 // Wa = W_hh_d + 0.5 W_ih_d  [k][j][g]
    int i2 = idx - (2048 + 16384);
    int k = i2 >> 8, j = (i2 >> 2) & 63, g = i2 & 3;
    int src = (g * 64 + j) * 64 + k;
    p.ws[OFF_AD + i2] = p.W_hh_d[src] + 0.5f * p.W_ih_d[src];
  } else if (idx < 2048 + 3 * 16384) {                 // Wb = 0.5 W_ih_d  [k][j][g]
    int i2 = idx - (2048 + 2 * 16384);
    int k = i2 >> 8, j = (i2 >> 2) & 63, g = i2 & 3;
    int src = (g * 64 + j) * 64 + k;
    p.ws[OFF_AD + 16384 + i2] = 0.5f * p.W_ih_d[src];
  } else if (idx < OFF_WOUT + 512) {                   // W_out_s[i][d][c] = W_out[d][c*8+i]
    int i2 = idx - OFF_WOUT;
    int i = i2 >> 6, d = (i2 >> 3) & 7, c = i2 & 7;
    p.ws[OFF_WOUT + i2] = p.W_out[d * 64 + c * 8 + i];
  } else if (idx < OFF_INP0 + 64) {                    // inp0 = start @ W_emb^T + b_emb
    int j = idx - OFF_INP0;
    float s = p.b_emb[j];
#pragma unroll
    for (int d = 0; d < 8; ++d) s += p.start[d] * p.W_emb[j * 8 + d];
    p.ws[OFF_INP0 + j] = s;
  } else if (idx < OFF_BE + 256) {
    int r = idx - OFF_BE;
    p.ws[OFF_BE + r] = p.b_ih_e[r] + p.b_hh_e[r];
  } else if (idx < OFF_BD + 256) {
    int r = idx - OFF_BD;
    p.ws[OFF_BD + r] = p.b_ih_d[r] + p.b_hh_d[r];
  }
}

// ---------------- encoder: split-K-8, 8 waves, 4 batches per block, grid 512 ----------------
struct EncP {
  const float* x; const float* ws;
  float* tmp_h; float* tmp_c;
};

__global__ __launch_bounds__(512, 4) void enc_kernel(EncP p) {
  __shared__ float4 part[8 * 4 * 64];     // [w][b][j]  32 KB
  __shared__ float  h_buf[4 * 68];        // [b][j] padded stride 68
  __shared__ float  sX[4][32][8];         // per-batch x chunk

  int tid = threadIdx.x;
  int wave = tid >> 6, lane = tid & 63;
  int ks = wave * 8;
  int bmine = blockIdx.x * 4 + wave;      // valid only for wave < 4

  float4 wih[8], whh[8];
#pragma unroll
  for (int kk = 0; kk < 8; ++kk) {
    wih[kk] = *(const float4*)(p.ws + OFF_AE_IH + (size_t)(kk * 64 + lane) * 4);
    whh[kk] = *(const float4*)(p.ws + OFF_AE_HH + (size_t)((ks + kk) * 64 + lane) * 4);
  }
  float4 be = make_float4(p.ws[OFF_BE + lane], p.ws[OFF_BE + 64 + lane],
                          p.ws[OFF_BE + 128 + lane], p.ws[OFF_BE + 192 + lane]);

  float c = 0.f, hcur = 0.f, vh = 0.f;

#pragma unroll 1
  for (int tc = 0; tc < 16; ++tc) {
    if (wave < 4) {                        // stage own batch's 32-step x chunk
      int tl = lane >> 1, half = lane & 1;
      const float* s = p.x + ((size_t)bmine * T_ + tc * 32 + tl) * 8 + half * 4;
      *(float4*)&sX[wave][tl][half * 4] = *(const float4*)s;
    }
#pragma unroll 1
    for (int tt = 0; tt < 32; ++tt) {
      float4 acc[4];
#pragma unroll
      for (int b = 0; b < 4; ++b) acc[b] = make_float4(0.f, 0.f, 0.f, 0.f);
#pragma unroll
      for (int kk = 0; kk < 8; ++kk) {
#pragma unroll
        for (int b = 0; b < 4; ++b) {
          float s = rdlane(vh, b * 8 + kk);
          acc[b].x = fmaf(whh[kk].x, s, acc[b].x);
          acc[b].y = fmaf(whh[kk].y, s, acc[b].y);
          acc[b].z = fmaf(whh[kk].z, s, acc[b].z);
          acc[b].w = fmaf(whh[kk].w, s, acc[b].w);
        }
      }
#pragma unroll
      for (int b = 0; b < 4; ++b) part[(wave * 4 + b) * 64 + lane] = acc[b];
      __syncthreads();

      if (wave < 4) {                      // finalize own batch
        float4 g = be;
        float4 xlo = *(const float4*)&sX[wave][tt][0];
        float4 xhi = *(const float4*)&sX[wave][tt][4];
        float xv[8] = {xlo.x, xlo.y, xlo.z, xlo.w, xhi.x, xhi.y, xhi.z, xhi.w};
#pragma unroll
        for (int k = 0; k < 8; ++k) {
          g.x = fmaf(wih[k].x, xv[k], g.x);
          g.y = fmaf(wih[k].y, xv[k], g.y);
          g.z = fmaf(wih[k].z, xv[k], g.z);
          g.w = fmaf(wih[k].w, xv[k], g.w);
        }
#pragma unroll
        for (int w = 0; w < 8; ++w) {
          float4 pw = part[(w * 4 + wave) * 64 + lane];
          g.x += pw.x; g.y += pw.y; g.z += pw.z; g.w += pw.w;
        }
        c = sigm(g.y) * c + sigm(g.x) * tanhf_(g.z);
        hcur = sigm(g.w) * tanhf_(c);
        h_buf[wave * 68 + lane] = hcur;
      }
      __syncthreads();
      vh = h_buf[((lane >> 3) & 3) * 68 + ks + (lane & 7)];
    }
  }

  if (wave < 4) {
    p.tmp_h[bmine * H_ + lane] = hcur;
    p.tmp_c[bmine * H_ + lane] = c;
  }
}

// ---------------- heads: mu/logvar/num/mass + decoder h0/c0 (one wave per batch) ----------------
struct HeadP {
  const float* tmp_h; const float* tmp_c;
  const float* W_mu; const float* b_mu; const float* W_lv; const float* b_lv;
  const float* W_l2h; const float* b_l2h; const float* W_l2h2; const float* b_l2h2;
  const float* W_seq; const float* b_seq; const float* W_seq2; const float* b_seq2;
  const float* W_m1; const float* b_m1; const float* W_m2; const float* b_m2;
  const float* W_m3; const float* b_m3;
  float* out_mu; float* out_lv; float* out_num; float* out_mass;
  float* ws_h0; float* ws_c0;
};

__global__ __launch_bounds__(256) void heads_kernel(HeadP p) {
  int tid = threadIdx.x;
  int wave = tid >> 6, lane = tid & 63;
  int b = blockIdx.x * 4 + wave;

  float hh = p.tmp_h[b * H_ + lane];
  float cc = p.tmp_c[b * H_ + lane];

  float muv = 0.f, lvv = 0.f;
#pragma unroll 1
  for (int l = 0; l < 16; ++l) {
    float pm = hh * p.W_mu[l * 128 + lane] + cc * p.W_mu[l * 128 + 64 + lane];
    float sm = wsum(pm);
    float pl = hh * p.W_lv[l * 128 + lane] + cc * p.W_lv[l * 128 + 64 + lane];
    float sl = wsum(pl);
    if (lane == l) { muv = sm + p.b_mu[l]; lvv = sl + p.b_lv[l]; }
  }
  if (lane < 16) {
    p.out_mu[b * L_ + lane] = muv;
    p.out_lv[b * L_ + lane] = lvv;
  }
  float mub[16];
#pragma unroll
  for (int l = 0; l < 16; ++l) mub[l] = __shfl(muv, l, 64);

  float s0 = p.b_l2h[lane], s1 = p.b_l2h2[lane];
#pragma unroll
  for (int l = 0; l < 16; ++l) {
    s0 = fmaf(mub[l], p.W_l2h[lane * 16 + l], s0);
    s1 = fmaf(mub[l], p.W_l2h2[lane * 16 + l], s1);
  }
  p.ws_h0[b * H_ + lane] = lrelu(s0);
  p.ws_c0[b * H_ + lane] = lrelu(s1);

  float sn = p.b_seq[lane];
#pragma unroll
  for (int l = 0; l < 16; ++l) sn = fmaf(mub[l], p.W_seq[lane * 16 + l], sn);
  sn = lrelu(sn);
  float rn = wsum(sn * p.W_seq2[lane]) + p.b_seq2[0];
  if (lane == 0) p.out_num[b] = fmaxf(rn, 0.f);

  float m1 = p.b_m1[lane];
#pragma unroll
  for (int l = 0; l < 16; ++l) m1 = fmaf(mub[l], p.W_m1[lane * 16 + l], m1);
  m1 = lrelu(m1);
  float m2 = p.b_m2[lane];
#pragma unroll
  for (int k = 0; k < 64; ++k) m2 = fmaf(rdlane(m1, k), p.W_m2[lane * 64 + k], m2);
  m2 = lrelu(m2);
  float r0 = wsum(m2 * p.W_m3[lane]) + p.b_m3[0];
  float r1 = wsum(m2 * p.W_m3[64 + lane]) + p.b_m3[1];
  if (lane == 0) {
    float mx = fmaxf(r0, r1);
    float e0 = __expf(r0 - mx), e1 = __expf(r1 - mx);
    float inv = 1.0f / (e0 + e1);
    p.out_mass[b * P_ + 0] = e0 * inv;
    p.out_mass[b * P_ + 1] = e1 * inv;
  }
}

// ---------------- decoder: split-K-8, Wa/Wb form, 4 batches per block, grid 512 ----------------
// FIRST step feeds a = 2*relu(inp0)-h0 (exact); later steps a = |h| via SALU s_and.
template<bool FIRST>
__device__ __forceinline__ void dec_partial(const float4 (&Wa)[8], const float4 (&Wb)[8],
                                            float vh, float va, float4 (&acc)[4]) {
#pragma unroll
  for (int kk = 0; kk < 8; ++kk) {
#pragma unroll
    for (int b = 0; b < 4; ++b) {
      int idx = b * 8 + kk;
      float s = rdlane(vh, idx);
      float a = FIRST ? rdlane(va, idx) : fabsf(s);
      acc[b].x = fmaf(Wa[kk].x, s, acc[b].x);
      acc[b].y = fmaf(Wa[kk].y, s, acc[b].y);
      acc[b].z = fmaf(Wa[kk].z, s, acc[b].z);
      acc[b].w = fmaf(Wa[kk].w, s, acc[b].w);
      acc[b].x = fmaf(Wb[kk].x, a, acc[b].x);
      acc[b].y = fmaf(Wb[kk].y, a, acc[b].y);
      acc[b].z = fmaf(Wb[kk].z, a, acc[b].z);
      acc[b].w = fmaf(Wb[kk].w, a, acc[b].w);
    }
  }
}

struct DecP {
  const float* ws; const float* b_out;
  float* out_recon;
};

__global__ __launch_bounds__(512, 4) void dec_kernel(DecP p) {
  __shared__ float4 part[8 * 4 * 64];     // 32 KB
  __shared__ float  h_buf[4 * 68];
  __shared__ float  sWout[512];

  int tid = threadIdx.x;
  int wave = tid >> 6, lane = tid & 63;
  int ks = wave * 8;
  int bmine = blockIdx.x * 4 + wave;      // valid only for wave < 4

  sWout[tid] = p.ws[OFF_WOUT + tid];

  float4 Wa[8], Wb[8];
#pragma unroll
  for (int kk = 0; kk < 8; ++kk) {
    Wa[kk] = *(const float4*)(p.ws + OFF_AD + (size_t)((ks + kk) * 64 + lane) * 4);
    Wb[kk] = *(const float4*)(p.ws + OFF_AD + 16384 + (size_t)((ks + kk) * 64 + lane) * 4);
  }
  float4 bd = make_float4(p.ws[OFF_BD + lane], p.ws[OFF_BD + 64 + lane],
                          p.ws[OFF_BD + 128 + lane], p.ws[OFF_BD + 192 + lane]);

  float c = 0.f;
  if (wave < 4) {
    c = p.ws[OFF_C0 + bmine * H_ + lane];
    h_buf[wave * 68 + lane] = p.ws[OFF_H0 + bmine * H_ + lane];
  }
  __syncthreads();
  float vh = h_buf[((lane >> 3) & 3) * 68 + ks + (lane & 7)];
  float rx0 = fmaxf(p.ws[OFF_INP0 + ks + (lane & 7)], 0.f);   // batch-independent
  float va0 = 2.f * rx0 - vh;

  int dd = lane & 7, cg = lane >> 3;
  float bod = p.b_out[dd];
  float* om = p.out_recon + (size_t)bmine * T_ * D_;

#pragma unroll 1
  for (int t = 0; t < T_; ++t) {
    float4 acc[4];
#pragma unroll
    for (int b = 0; b < 4; ++b) acc[b] = make_float4(0.f, 0.f, 0.f, 0.f);
    if (t == 0) dec_partial<true >(Wa, Wb, vh, va0, acc);
    else        dec_partial<false>(Wa, Wb, vh, 0.f, acc);
#pragma unroll
    for (int b = 0; b < 4; ++b) part[(wave * 4 + b) * 64 + lane] = acc[b];
    __syncthreads();

    if (wave < 4) {
      float4 g = bd;
#pragma unroll
      for (int w = 0; w < 8; ++w) {
        float4 pw = part[(w * 4 + wave) * 64 + lane];
        g.x += pw.x; g.y += pw.y; g.z += pw.z; g.w += pw.w;
      }
      c = sigm(g.y) * c + sigm(g.x) * tanhf_(g.z);
      float h = sigm(g.w) * tanhf_(c);

      float y = 0.f;
#pragma unroll
      for (int i = 0; i < 8; ++i)
        y = fmaf(sWout[i * 64 + dd * 8 + cg], __shfl(h, cg * 8 + i, 64), y);
      y += __shfl_xor(y, 8, 64); y += __shfl_xor(y, 16, 64); y += __shfl_xor(y, 32, 64);
      if (lane < 8) om[t * 8 + lane] = y + bod;

      h_buf[wave * 68 + lane] = h;
    }
    __syncthreads();
    vh = h_buf[((lane >> 3) & 3) * 68 + ks + (lane & 7)];
  }
}

// ---------------- host ----------------
extern "C" void kernel_launch(void* const* d_in, const int* in_sizes, int n_in,
                              void* d_out, int out_size, void* d_ws, size_t ws_size,
                              hipStream_t stream) {
  const float* x       = (const float*)d_in[0];
  const float* start   = (const float*)d_in[1];
  const float* W_ih_e  = (const float*)d_in[2];
  const float* W_hh_e  = (const float*)d_in[3];
  const float* b_ih_e  = (const float*)d_in[4];
  const float* b_hh_e  = (const float*)d_in[5];
  const float* W_mu    = (const float*)d_in[6];
  const float* b_mu    = (const float*)d_in[7];
  const float* W_lv    = (const float*)d_in[8];
  const float* b_lv    = (const float*)d_in[9];
  const float* W_l2h   = (const float*)d_in[10];
  const float* b_l2h   = (const float*)d_in[11];
  const float* W_l2h2  = (const float*)d_in[12];
  const float* b_l2h2  = (const float*)d_in[13];
  const float* W_emb   = (const float*)d_in[14];
  const float* b_emb   = (const float*)d_in[15];
  const float* W_ih_d  = (const float*)d_in[16];
  const float* W_hh_d  = (const float*)d_in[17];
  const float* b_ih_d  = (const float*)d_in[18];
  const float* b_hh_d  = (const float*)d_in[19];
  const float* W_out   = (const float*)d_in[20];
  const float* b_out   = (const float*)d_in[21];
  const float* W_seq   = (const float*)d_in[22];
  const float* b_seq   = (const float*)d_in[23];
  const float* W_seq2  = (const float*)d_in[24];
  const float* b_seq2  = (const float*)d_in[25];
  const float* W_m1    = (const float*)d_in[26];
  const float* b_m1    = (const float*)d_in[27];
  const float* W_m2    = (const float*)d_in[28];
  const float* b_m2    = (const float*)d_in[29];
  const float* W_m3    = (const float*)d_in[30];
  const float* b_m3    = (const float*)d_in[31];

  float* ws  = (float*)d_ws;
  float* out = (float*)d_out;
  float* out_mu   = out + (size_t)B_ * T_ * D_;
  float* out_lv   = out_mu + B_ * L_;
  float* out_num  = out_lv + B_ * L_;
  float* out_mass = out_num + B_;

  // hT/cT scratch lives in the recon area of d_out (dec overwrites it afterwards)
  float* tmp_h = out;                   // B*H floats
  float* tmp_c = out + B_ * H_;         // B*H floats

  PrepP pp{W_ih_e, W_hh_e, b_ih_e, b_hh_e, W_ih_d, W_hh_d, b_ih_d, b_hh_d,
           W_out, start, W_emb, b_emb, ws};
  hipLaunchKernelGGL(prep_kernel, dim3(205), dim3(256), 0, stream, pp);

  EncP ep{x, ws, tmp_h, tmp_c};
  hipLaunchKernelGGL(enc_kernel, dim3(512), dim3(512), 0, stream, ep);

  HeadP hp{tmp_h, tmp_c, W_mu, b_mu, W_lv, b_lv, W_l2h, b_l2h, W_l2h2, b_l2h2,
           W_seq, b_seq, W_seq2, b_seq2, W_m1, b_m1, W_m2, b_m2, W_m3, b_m3,
           out_mu, out_lv, out_num, out_mass, ws + OFF_H0, ws + OFF_C0};
  hipLaunchKernelGGL(heads_kernel, dim3(512), dim3(256), 0, stream, hp);

  DecP dp{ws, b_out, out};
  hipLaunchKernelGGL(dec_kernel, dim3(512), dim3(512), 0, stream, dp);
}

// Round 7
// 1556.302 us; speedup vs baseline: 7.0559x; 1.3246x over previous
//
#include <hip/hip_runtime.h>
#include <math.h>

#define B_ 2048
#define T_ 512
#define D_ 8
#define H_ 64
#define L_ 16
#define P_ 2

// ---- workspace layout (float offsets) ----
#define OFF_AE_IH   0                       // enc ih [k=8][j=64][g=4]   = 2048
#define OFF_AE_HH   2048                    // enc hh [k=64][j=64][g=4]  = 16384
#define OFF_WCH     18432                   // dec Wcat hi: ushort[256][128] -> 16384 float slots
#define OFF_WCL     34816                   // dec Wcat lo: 16384 float slots
#define OFF_WOH     51200                   // Wout-cat hi: ushort[16][64] -> 512 float slots
#define OFF_WOL     51712                   // Wout-cat lo: 512
#define OFF_INP0    52224                   // 64
#define OFF_BE      52288                   // 256
#define OFF_BD      52544                   // 256  (bd[g*64+u])
#define OFF_H0      52800                   // B*H
#define OFF_C0      (OFF_H0 + B_*H_)

typedef __attribute__((ext_vector_type(8))) short s8bf;   // 8 bf16 (4 VGPRs)
typedef __attribute__((ext_vector_type(4))) float f32x4;  // MFMA acc

union FragU { uint u[4]; s8bf v; };
__device__ __forceinline__ s8bf mkfrag(uint a, uint b, uint c, uint d) {
  FragU x; x.u[0] = a; x.u[1] = b; x.u[2] = c; x.u[3] = d; return x.v;
}
__device__ __forceinline__ uint cvtpk(float a, float b) {  // [15:0]=bf16(a), [31:16]=bf16(b)
  uint d; asm("v_cvt_pk_bf16_f32 %0, %1, %2" : "=v"(d) : "v"(a), "v"(b)); return d;
}
// split 8 f32 -> packed bf16 hi (4 dwords) + lo (4 dwords)
#define SPLIT8(DH, DL, V, BASE) do { \
  _Pragma("unroll") \
  for (int r_ = 0; r_ < 4; ++r_) { \
    uint hp_ = cvtpk(V[BASE + 2*r_], V[BASE + 2*r_ + 1]); \
    float e0_ = __uint_as_float(hp_ << 16); \
    float e1_ = __uint_as_float(hp_ & 0xffff0000u); \
    DH[r_] = hp_; \
    DL[r_] = cvtpk(V[BASE + 2*r_] - e0_, V[BASE + 2*r_ + 1] - e1_); \
  } } while (0)

__device__ __forceinline__ float sigm(float x) { return 1.0f / (1.0f + __expf(-x)); }
__device__ __forceinline__ float tanhf_(float x) {
  float ax = fabsf(x);
  float e  = __expf(-2.0f * ax);
  float r  = (1.0f - e) / (1.0f + e);
  return copysignf(r, x);
}
__device__ __forceinline__ float lrelu(float x) { return x >= 0.0f ? x : 0.01f * x; }
__device__ __forceinline__ float rdlane(float v, int l) {
  return __int_as_float(__builtin_amdgcn_readlane(__float_as_int(v), l));
}
__device__ __forceinline__ float wsum(float v) {
#pragma unroll
  for (int off = 32; off > 0; off >>= 1) v += __shfl_xor(v, off, 64);
  return v;
}
__device__ __forceinline__ ushort bf16rne(float x) {
  uint b = __float_as_uint(x);
  uint r = b + 0x7fffu + ((b >> 16) & 1u);
  return (ushort)(r >> 16);
}

// ---------------- prep ----------------
// Dec weights: Wcat[r][k], r=16t+4q+g <-> (unit u=4t+q, gate g); k<64: Wa=Whh+0.5Wih (on h),
// k>=64: Wb=0.5Wih (on |h|). Stored as split-bf16 hi/lo. Wout-cat: rows d(0..7)+zero-pad to 16.
struct PrepP {
  const float* W_ih_e; const float* W_hh_e; const float* b_ih_e; const float* b_hh_e;
  const float* W_ih_d; const float* W_hh_d; const float* b_ih_d; const float* b_hh_d;
  const float* W_out;  const float* start;  const float* W_emb;  const float* b_emb;
  float* ws;
};

__global__ __launch_bounds__(256) void prep_kernel(PrepP p) {
  int idx = blockIdx.x * 256 + threadIdx.x;
  if (idx < 2048) {                                    // enc Ae_ih [k][j][g]
    int k = idx >> 8, j = (idx >> 2) & 63, g = idx & 3;
    p.ws[OFF_AE_IH + idx] = p.W_ih_e[(g * 64 + j) * 8 + k];
  } else if (idx < 18432) {                            // enc Ae_hh [k][j][g]
    int i2 = idx - 2048;
    int k = i2 >> 8, j = (i2 >> 2) & 63, g = i2 & 3;
    p.ws[OFF_AE_HH + i2] = p.W_hh_e[(g * 64 + j) * 64 + k];
  } else if (idx < 18432 + 32768) {                    // dec Wcat hi/lo
    int e = idx - 18432;
    int r = e >> 7, k = e & 127;
    int t = r >> 4, qq = (r >> 2) & 3, g = r & 3;
    int u = 4 * t + qq;
    float w = (k < 64) ? (p.W_hh_d[(g * 64 + u) * 64 + k] + 0.5f * p.W_ih_d[(g * 64 + u) * 64 + k])
                       : (0.5f * p.W_ih_d[(g * 64 + u) * 64 + (k - 64)]);
    ushort hi = bf16rne(w);
    float hif = __uint_as_float(((uint)hi) << 16);
    ushort lo = bf16rne(w - hif);
    ((ushort*)(p.ws + OFF_WCH))[e] = hi;
    ((ushort*)(p.ws + OFF_WCL))[e] = lo;
  } else if (idx < 18432 + 32768 + 1024) {             // Wout-cat hi/lo (16 x 64)
    int e = idx - (18432 + 32768);
    int d = e >> 6, k = e & 63;
    float w = (d < 8) ? p.W_out[d * 64 + k] : 0.f;
    ushort hi = bf16rne(w);
    float hif = __uint_as_float(((uint)hi) << 16);
    ushort lo = bf16rne(w - hif);
    ((ushort*)(p.ws + OFF_WOH))[e] = hi;
    ((ushort*)(p.ws + OFF_WOL))[e] = lo;
  } else if (idx < OFF_INP0 + 64) {                    // inp0
    int j = idx - OFF_INP0;
    float s = p.b_emb[j];
#pragma unroll
    for (int d = 0; d < 8; ++d) s += p.start[d] * p.W_emb[j * 8 + d];
    p.ws[OFF_INP0 + j] = s;
  } else if (idx < OFF_BE + 256) {
    int r = idx - OFF_BE;
    p.ws[OFF_BE + r] = p.b_ih_e[r] + p.b_hh_e[r];
  } else if (idx < OFF_BD + 256) {
    int r = idx - OFF_BD;
    p.ws[OFF_BD + r] = p.b_ih_d[r] + p.b_hh_d[r];
  }
}

// ---------------- encoder: unchanged (split-K-8, 8 waves, 4 batches/block) ----------------
struct EncP {
  const float* x; const float* ws;
  float* tmp_h; float* tmp_c;
};

__global__ __launch_bounds__(512, 4) void enc_kernel(EncP p) {
  __shared__ float4 part[8 * 4 * 64];
  __shared__ float  h_buf[4 * 68];
  __shared__ float  sX[4][32][8];

  int tid = threadIdx.x;
  int wave = tid >> 6, lane = tid & 63;
  int ks = wave * 8;
  int bmine = blockIdx.x * 4 + wave;

  float4 wih[8], whh[8];
#pragma unroll
  for (int kk = 0; kk < 8; ++kk) {
    wih[kk] = *(const float4*)(p.ws + OFF_AE_IH + (size_t)(kk * 64 + lane) * 4);
    whh[kk] = *(const float4*)(p.ws + OFF_AE_HH + (size_t)((ks + kk) * 64 + lane) * 4);
  }
  float4 be = make_float4(p.ws[OFF_BE + lane], p.ws[OFF_BE + 64 + lane],
                          p.ws[OFF_BE + 128 + lane], p.ws[OFF_BE + 192 + lane]);

  float c = 0.f, hcur = 0.f, vh = 0.f;

#pragma unroll 1
  for (int tc = 0; tc < 16; ++tc) {
    if (wave < 4) {
      int tl = lane >> 1, half = lane & 1;
      const float* s = p.x + ((size_t)bmine * T_ + tc * 32 + tl) * 8 + half * 4;
      *(float4*)&sX[wave][tl][half * 4] = *(const float4*)s;
    }
#pragma unroll 1
    for (int tt = 0; tt < 32; ++tt) {
      float4 acc[4];
#pragma unroll
      for (int b = 0; b < 4; ++b) acc[b] = make_float4(0.f, 0.f, 0.f, 0.f);
#pragma unroll
      for (int kk = 0; kk < 8; ++kk) {
#pragma unroll
        for (int b = 0; b < 4; ++b) {
          float s = rdlane(vh, b * 8 + kk);
          acc[b].x = fmaf(whh[kk].x, s, acc[b].x);
          acc[b].y = fmaf(whh[kk].y, s, acc[b].y);
          acc[b].z = fmaf(whh[kk].z, s, acc[b].z);
          acc[b].w = fmaf(whh[kk].w, s, acc[b].w);
        }
      }
#pragma unroll
      for (int b = 0; b < 4; ++b) part[(wave * 4 + b) * 64 + lane] = acc[b];
      __syncthreads();

      if (wave < 4) {
        float4 g = be;
        float4 xlo = *(const float4*)&sX[wave][tt][0];
        float4 xhi = *(const float4*)&sX[wave][tt][4];
        float xv[8] = {xlo.x, xlo.y, xlo.z, xlo.w, xhi.x, xhi.y, xhi.z, xhi.w};
#pragma unroll
        for (int k = 0; k < 8; ++k) {
          g.x = fmaf(wih[k].x, xv[k], g.x);
          g.y = fmaf(wih[k].y, xv[k], g.y);
          g.z = fmaf(wih[k].z, xv[k], g.z);
          g.w = fmaf(wih[k].w, xv[k], g.w);
        }
#pragma unroll
        for (int w = 0; w < 8; ++w) {
          float4 pw = part[(w * 4 + wave) * 64 + lane];
          g.x += pw.x; g.y += pw.y; g.z += pw.z; g.w += pw.w;
        }
        c = sigm(g.y) * c + sigm(g.x) * tanhf_(g.z);
        hcur = sigm(g.w) * tanhf_(c);
        h_buf[wave * 68 + lane] = hcur;
      }
      __syncthreads();
      vh = h_buf[((lane >> 3) & 3) * 68 + ks + (lane & 7)];
    }
  }

  if (wave < 4) {
    p.tmp_h[bmine * H_ + lane] = hcur;
    p.tmp_c[bmine * H_ + lane] = c;
  }
}

// ---------------- heads: unchanged ----------------
struct HeadP {
  const float* tmp_h; const float* tmp_c;
  const float* W_mu; const float* b_mu; const float* W_lv; const float* b_lv;
  const float* W_l2h; const float* b_l2h; const float* W_l2h2; const float* b_l2h2;
  const float* W_seq; const float* b_seq; const float* W_seq2; const float* b_seq2;
  const float* W_m1; const float* b_m1; const float* W_m2; const float* b_m2;
  const float* W_m3; const float* b_m3;
  float* out_mu; float* out_lv; float* out_num; float* out_mass;
  float* ws_h0; float* ws_c0;
};

__global__ __launch_bounds__(256) void heads_kernel(HeadP p) {
  int tid = threadIdx.x;
  int wave = tid >> 6, lane = tid & 63;
  int b = blockIdx.x * 4 + wave;

  float hh = p.tmp_h[b * H_ + lane];
  float cc = p.tmp_c[b * H_ + lane];

  float muv = 0.f, lvv = 0.f;
#pragma unroll 1
  for (int l = 0; l < 16; ++l) {
    float pm = hh * p.W_mu[l * 128 + lane] + cc * p.W_mu[l * 128 + 64 + lane];
    float sm = wsum(pm);
    float pl = hh * p.W_lv[l * 128 + lane] + cc * p.W_lv[l * 128 + 64 + lane];
    float sl = wsum(pl);
    if (lane == l) { muv = sm + p.b_mu[l]; lvv = sl + p.b_lv[l]; }
  }
  if (lane < 16) {
    p.out_mu[b * L_ + lane] = muv;
    p.out_lv[b * L_ + lane] = lvv;
  }
  float mub[16];
#pragma unroll
  for (int l = 0; l < 16; ++l) mub[l] = __shfl(muv, l, 64);

  float s0 = p.b_l2h[lane], s1 = p.b_l2h2[lane];
#pragma unroll
  for (int l = 0; l < 16; ++l) {
    s0 = fmaf(mub[l], p.W_l2h[lane * 16 + l], s0);
    s1 = fmaf(mub[l], p.W_l2h2[lane * 16 + l], s1);
  }
  p.ws_h0[b * H_ + lane] = lrelu(s0);
  p.ws_c0[b * H_ + lane] = lrelu(s1);

  float sn = p.b_seq[lane];
#pragma unroll
  for (int l = 0; l < 16; ++l) sn = fmaf(mub[l], p.W_seq[lane * 16 + l], sn);
  sn = lrelu(sn);
  float rn = wsum(sn * p.W_seq2[lane]) + p.b_seq2[0];
  if (lane == 0) p.out_num[b] = fmaxf(rn, 0.f);

  float m1 = p.b_m1[lane];
#pragma unroll
  for (int l = 0; l < 16; ++l) m1 = fmaf(mub[l], p.W_m1[lane * 16 + l], m1);
  m1 = lrelu(m1);
  float m2 = p.b_m2[lane];
#pragma unroll
  for (int k = 0; k < 64; ++k) m2 = fmaf(rdlane(m1, k), p.W_m2[lane * 64 + k], m2);
  m2 = lrelu(m2);
  float r0 = wsum(m2 * p.W_m3[lane]) + p.b_m3[0];
  float r1 = wsum(m2 * p.W_m3[64 + lane]) + p.b_m3[1];
  if (lane == 0) {
    float mx = fmaxf(r0, r1);
    float e0 = __expf(r0 - mx), e1 = __expf(r1 - mx);
    float inv = 1.0f / (e0 + e1);
    p.out_mass[b * P_ + 0] = e0 * inv;
    p.out_mass[b * P_ + 1] = e1 * inv;
  }
}

// ---------------- decoder: MFMA, 16 batches/block, grid 128, 8 waves ----------------
// A = Wcat (static frags, 2 M-tiles/wave), B = X=[h;|h|] split-bf16, 3-pass per k-step.
// C/D layout: col=lane&15 (batch), row=4*(lane>>4)+reg (gate within tile).
// A layout: row=lane&15, k=8*(lane>>4)+j.  B: col=lane&15, k same.
struct DecP {
  const float* ws; const float* b_out;
  float* out_recon;
};

__global__ __launch_bounds__(512) void dec_kernel(DecP p) {
  __shared__ float hx[16 * 68];           // h' exchange, padded stride 68

  int tid = threadIdx.x, wave = tid >> 6, lane = tid & 63;
  int q = lane >> 4, col = lane & 15;
  int gb = blockIdx.x * 16 + col;         // global batch (B/C column role)

  // static A-frags: tiles 2w, 2w+1
  uint AH[2][4][4], AL[2][4][4];
  {
    const ushort* WH = (const ushort*)(p.ws + OFF_WCH);
    const ushort* WL = (const ushort*)(p.ws + OFF_WCL);
#pragma unroll
    for (int t2 = 0; t2 < 2; ++t2)
#pragma unroll
      for (int ks = 0; ks < 4; ++ks) {
        int off = (16 * (2 * wave + t2) + col) * 128 + 32 * ks + 8 * q;
        uint4 h4 = *(const uint4*)(WH + off);
        AH[t2][ks][0] = h4.x; AH[t2][ks][1] = h4.y; AH[t2][ks][2] = h4.z; AH[t2][ks][3] = h4.w;
        uint4 l4 = *(const uint4*)(WL + off);
        AL[t2][ks][0] = l4.x; AL[t2][ks][1] = l4.y; AL[t2][ks][2] = l4.z; AL[t2][ks][3] = l4.w;
      }
  }
  // wave 0: Wout frags (A rows = d, K=64 over h)
  uint WOH[2][4], WOL[2][4];
  if (wave == 0) {
    const ushort* WH = (const ushort*)(p.ws + OFF_WOH);
    const ushort* WL = (const ushort*)(p.ws + OFF_WOL);
#pragma unroll
    for (int ks = 0; ks < 2; ++ks) {
      int off = col * 64 + 32 * ks + 8 * q;
      uint4 h4 = *(const uint4*)(WH + off);
      WOH[ks][0] = h4.x; WOH[ks][1] = h4.y; WOH[ks][2] = h4.z; WOH[ks][3] = h4.w;
      uint4 l4 = *(const uint4*)(WL + off);
      WOL[ks][0] = l4.x; WOL[ks][1] = l4.y; WOL[ks][2] = l4.z; WOL[ks][3] = l4.w;
    }
  }

  // epilogue constants: this lane owns (batch=col, units u(t2)=8*wave+4*t2+q)
  float bdv[2][4], cst[2];
#pragma unroll
  for (int t2 = 0; t2 < 2; ++t2) {
    int u = 8 * wave + 4 * t2 + q;
#pragma unroll
    for (int g = 0; g < 4; ++g) bdv[t2][g] = p.ws[OFF_BD + g * 64 + u];
    cst[t2] = p.ws[OFF_C0 + gb * 64 + u];
  }
  float bov[4];
#pragma unroll
  for (int g = 0; g < 4; ++g) bov[g] = (q < 2) ? p.b_out[4 * q + g] : 0.f;

  // initial B-frags from h0 and a0 = 2*relu(inp0)-h0  (X0 = [h0; a0])
  uint BH[4][4], BL[4][4];
  {
    float hv[16], av[16];
#pragma unroll
    for (int j = 0; j < 8; ++j) {
      hv[j]     = p.ws[OFF_H0 + gb * 64 + 8 * q + j];
      hv[8 + j] = p.ws[OFF_H0 + gb * 64 + 32 + 8 * q + j];
      float i0 = p.ws[OFF_INP0 + 8 * q + j];
      float i1 = p.ws[OFF_INP0 + 32 + 8 * q + j];
      av[j]     = 2.f * fmaxf(i0, 0.f) - hv[j];
      av[8 + j] = 2.f * fmaxf(i1, 0.f) - hv[8 + j];
    }
    SPLIT8(BH[0], BL[0], hv, 0);
    SPLIT8(BH[1], BL[1], hv, 8);
    SPLIT8(BH[2], BL[2], av, 0);
    SPLIT8(BH[3], BL[3], av, 8);
  }

#pragma unroll 1
  for (int t = 0; t < T_; ++t) {
    // ---- gate GEMM: 3-pass split-bf16 ----
    f32x4 acc0 = {0.f, 0.f, 0.f, 0.f}, acc1 = {0.f, 0.f, 0.f, 0.f};
#pragma unroll
    for (int ks = 0; ks < 4; ++ks) {
      s8bf bh = mkfrag(BH[ks][0], BH[ks][1], BH[ks][2], BH[ks][3]);
      s8bf bl = mkfrag(BL[ks][0], BL[ks][1], BL[ks][2], BL[ks][3]);
      s8bf a0h = mkfrag(AH[0][ks][0], AH[0][ks][1], AH[0][ks][2], AH[0][ks][3]);
      s8bf a0l = mkfrag(AL[0][ks][0], AL[0][ks][1], AL[0][ks][2], AL[0][ks][3]);
      s8bf a1h = mkfrag(AH[1][ks][0], AH[1][ks][1], AH[1][ks][2], AH[1][ks][3]);
      s8bf a1l = mkfrag(AL[1][ks][0], AL[1][ks][1], AL[1][ks][2], AL[1][ks][3]);
      acc0 = __builtin_amdgcn_mfma_f32_16x16x32_bf16(a0h, bh, acc0, 0, 0, 0);
      acc0 = __builtin_amdgcn_mfma_f32_16x16x32_bf16(a0h, bl, acc0, 0, 0, 0);
      acc0 = __builtin_amdgcn_mfma_f32_16x16x32_bf16(a0l, bh, acc0, 0, 0, 0);
      acc1 = __builtin_amdgcn_mfma_f32_16x16x32_bf16(a1h, bh, acc1, 0, 0, 0);
      acc1 = __builtin_amdgcn_mfma_f32_16x16x32_bf16(a1h, bl, acc1, 0, 0, 0);
      acc1 = __builtin_amdgcn_mfma_f32_16x16x32_bf16(a1l, bh, acc1, 0, 0, 0);
    }
    // ---- epilogue: lane owns (batch=col, units 8w+4t2+q) ----
#pragma unroll
    for (int t2 = 0; t2 < 2; ++t2) {
      f32x4 g = t2 ? acc1 : acc0;
      float ii = g[0] + bdv[t2][0];
      float ff = g[1] + bdv[t2][1];
      float gg = g[2] + bdv[t2][2];
      float oo = g[3] + bdv[t2][3];
      float cn = sigm(ff) * cst[t2] + sigm(ii) * tanhf_(gg);
      cst[t2] = cn;
      float hn = sigm(oo) * tanhf_(cn);
      hx[68 * col + 8 * wave + 4 * t2 + q] = hn;
    }
    __syncthreads();

    // ---- B-prep for next step (+ y output on wave 0) ----
    {
      const float* hr = &hx[68 * col + 8 * q];
      float4 v0 = *(const float4*)hr;
      float4 v1 = *(const float4*)(hr + 4);
      float4 v2 = *(const float4*)(hr + 32);
      float4 v3 = *(const float4*)(hr + 36);
      float hv[16] = {v0.x, v0.y, v0.z, v0.w, v1.x, v1.y, v1.z, v1.w,
                      v2.x, v2.y, v2.z, v2.w, v3.x, v3.y, v3.z, v3.w};
      SPLIT8(BH[0], BL[0], hv, 0);
      SPLIT8(BH[1], BL[1], hv, 8);
#pragma unroll
      for (int r = 0; r < 4; ++r) {       // |h| halves: abs(hi), sign-fixed lo
        uint s0 = BH[0][r] & 0x80008000u;
        BH[2][r] = BH[0][r] & 0x7fff7fffu;
        BL[2][r] = BL[0][r] ^ s0;
        uint s1 = BH[1][r] & 0x80008000u;
        BH[3][r] = BH[1][r] & 0x7fff7fffu;
        BL[3][r] = BL[1][r] ^ s1;
      }
      if (wave == 0) {                    // y_t = Wout * h^{(t+1)} via same B-frags
        f32x4 ya = {0.f, 0.f, 0.f, 0.f};
#pragma unroll
        for (int ks = 0; ks < 2; ++ks) {
          s8bf bh = mkfrag(BH[ks][0], BH[ks][1], BH[ks][2], BH[ks][3]);
          s8bf bl = mkfrag(BL[ks][0], BL[ks][1], BL[ks][2], BL[ks][3]);
          s8bf wh = mkfrag(WOH[ks][0], WOH[ks][1], WOH[ks][2], WOH[ks][3]);
          s8bf wl = mkfrag(WOL[ks][0], WOL[ks][1], WOL[ks][2], WOL[ks][3]);
          ya = __builtin_amdgcn_mfma_f32_16x16x32_bf16(wh, bh, ya, 0, 0, 0);
          ya = __builtin_amdgcn_mfma_f32_16x16x32_bf16(wh, bl, ya, 0, 0, 0);
          ya = __builtin_amdgcn_mfma_f32_16x16x32_bf16(wl, bh, ya, 0, 0, 0);
        }
        if (q < 2) {
          float* od = p.out_recon + ((size_t)gb * T_ + t) * D_ + 4 * q;
          od[0] = ya[0] + bov[0];
          od[1] = ya[1] + bov[1];
          od[2] = ya[2] + bov[2];
          od[3] = ya[3] + bov[3];
        }
      }
    }
    __syncthreads();
  }
}

// ---------------- host ----------------
extern "C" void kernel_launch(void* const* d_in, const int* in_sizes, int n_in,
                              void* d_out, int out_size, void* d_ws, size_t ws_size,
                              hipStream_t stream) {
  const float* x       = (const float*)d_in[0];
  const float* start   = (const float*)d_in[1];
  const float* W_ih_e  = (const float*)d_in[2];
  const float* W_hh_e  = (const float*)d_in[3];
  const float* b_ih_e  = (const float*)d_in[4];
  const float* b_hh_e  = (const float*)d_in[5];
  const float* W_mu    = (const float*)d_in[6];
  const float* b_mu    = (const float*)d_in[7];
  const float* W_lv    = (const float*)d_in[8];
  const float* b_lv    = (const float*)d_in[9];
  const float* W_l2h   = (const float*)d_in[10];
  const float* b_l2h   = (const float*)d_in[11];
  const float* W_l2h2  = (const float*)d_in[12];
  const float* b_l2h2  = (const float*)d_in[13];
  const float* W_emb   = (const float*)d_in[14];
  const float* b_emb   = (const float*)d_in[15];
  const float* W_ih_d  = (const float*)d_in[16];
  const float* W_hh_d  = (const float*)d_in[17];
  const float* b_ih_d  = (const float*)d_in[18];
  const float* b_hh_d  = (const float*)d_in[19];
  const float* W_out   = (const float*)d_in[20];
  const float* b_out   = (const float*)d_in[21];
  const float* W_seq   = (const float*)d_in[22];
  const float* b_seq   = (const float*)d_in[23];
  const float* W_seq2  = (const float*)d_in[24];
  const float* b_seq2  = (const float*)d_in[25];
  const float* W_m1    = (const float*)d_in[26];
  const float* b_m1    = (const float*)d_in[27];
  const float* W_m2    = (const float*)d_in[28];
  const float* b_m2    = (const float*)d_in[29];
  const float* W_m3    = (const float*)d_in[30];
  const float* b_m3    = (const float*)d_in[31];

  float* ws  = (float*)d_ws;
  float* out = (float*)d_out;
  float* out_mu   = out + (size_t)B_ * T_ * D_;
  float* out_lv   = out_mu + B_ * L_;
  float* out_num  = out_lv + B_ * L_;
  float* out_mass = out_num + B_;

  // hT/cT scratch in recon area of d_out (dec overwrites afterwards)
  float* tmp_h = out;
  float* tmp_c = out + B_ * H_;

  PrepP pp{W_ih_e, W_hh_e, b_ih_e, b_hh_e, W_ih_d, W_hh_d, b_ih_d, b_hh_d,
           W_out, start, W_emb, b_emb, ws};
  hipLaunchKernelGGL(prep_kernel, dim3(207), dim3(256), 0, stream, pp);

  EncP ep{x, ws, tmp_h, tmp_c};
  hipLaunchKernelGGL(enc_kernel, dim3(512), dim3(512), 0, stream, ep);

  HeadP hp{tmp_h, tmp_c, W_mu, b_mu, W_lv, b_lv, W_l2h, b_l2h, W_l2h2, b_l2h2,
           W_seq, b_seq, W_seq2, b_seq2, W_m1, b_m1, W_m2, b_m2, W_m3, b_m3,
           out_mu, out_lv, out_num, out_mass, ws + OFF_H0, ws + OFF_C0};
  hipLaunchKernelGGL(heads_kernel, dim3(512), dim3(256), 0, stream, hp);

  DecP dp{ws, b_out, out};
  hipLaunchKernelGGL(dec_kernel, dim3(128), dim3(512), 0, stream, dp);
}